// Round 1
// baseline (4250.148 us; speedup 1.0000x reference)
//
#include <hip/hip_runtime.h>
#include <math.h>

#define NB      32
#define NNODES  131072
#define NEDGES  393216

// ---------------- workspace layout (float offsets) ----------------
// X  : [N,128] node features in/out per layer (in-place across a layer)
// U  : max(pool1 = 32*32*130*130, N*130)  -- pool1 aliases U (dead by L1)
// V  : [N,130]
static const size_t OFF_X     = 0;                       // 16,777,216
static const size_t OFF_U     = 16777216;                // 17,305,600
static const size_t OFF_V     = OFF_U + 17305600;        // 17,039,360
static const size_t OFF_AEXP  = OFF_V + 17039360;        // E*2
static const size_t OFF_DEN   = OFF_AEXP + 786432;       // N*2
static const size_t OFF_WU    = OFF_DEN + 262144;        // 128*130
static const size_t OFF_WV    = OFF_WU + 16640;
static const size_t OFF_UB    = OFF_WV + 16640;          // 256
static const size_t OFF_STATS = OFF_UB + 256;            // 64 doubles (128 floats)
static const size_t OFF_SS    = OFF_STATS + 128;         // scale[32], shift[32]
static const size_t OFF_GPOOL = OFF_SS + 64;             // 32*128
static const size_t OFF_AMAX  = OFF_GPOOL + 4096;        // 2 uints
// total ~52.2M floats ~= 209 MB

// monotone float<->uint encoding for atomicMax on floats
__device__ inline unsigned enc_f(float f) {
  int b = __float_as_int(f);
  unsigned u = (unsigned)b;
  return (b >= 0) ? (u | 0x80000000u) : ~u;
}
__device__ inline float dec_f(unsigned e) {
  unsigned b = (e & 0x80000000u) ? (e & 0x7FFFFFFFu) : ~e;
  return __int_as_float((int)b);
}

// ---------------- conv block 1 ----------------
__global__ void conv1_stats_k(const float* __restrict__ x, const float* __restrict__ W1,
                              const float* __restrict__ b1, double* __restrict__ stats) {
  __shared__ float sb1[4], sb2[4];
  int plane = blockIdx.y;                   // b*32+c
  int b = plane >> 5, c = plane & 31;
  float w[27];
#pragma unroll
  for (int i = 0; i < 27; ++i) w[i] = W1[c * 27 + i];
  float bias = b1[c];
  const float* xb = x + (size_t)b * 3 * 68644;   // 262*262
  float s1 = 0.f, s2 = 0.f;
  for (int p = blockIdx.x * 256 + threadIdx.x; p < 67600; p += gridDim.x * 256) {
    int y = p / 260, xx = p - y * 260;
    float acc = bias;
#pragma unroll
    for (int ci = 0; ci < 3; ++ci) {
      const float* ip = xb + ci * 68644 + y * 262 + xx;
#pragma unroll
      for (int dy = 0; dy < 3; ++dy)
#pragma unroll
        for (int dx = 0; dx < 3; ++dx)
          acc += ip[dy * 262 + dx] * w[ci * 9 + dy * 3 + dx];
    }
    s1 += acc; s2 += acc * acc;
  }
#pragma unroll
  for (int o = 32; o > 0; o >>= 1) { s1 += __shfl_down(s1, o); s2 += __shfl_down(s2, o); }
  int wv = threadIdx.x >> 6;
  if ((threadIdx.x & 63) == 0) { sb1[wv] = s1; sb2[wv] = s2; }
  __syncthreads();
  if (threadIdx.x == 0) {
    float t1 = 0.f, t2 = 0.f;
    for (int i = 0; i < 4; ++i) { t1 += sb1[i]; t2 += sb2[i]; }
    atomicAdd(&stats[c * 2 + 0], (double)t1);
    atomicAdd(&stats[c * 2 + 1], (double)t2);
  }
}

__global__ void bn_finalize_k(const double* __restrict__ stats, const float* __restrict__ g,
                              const float* __restrict__ be, float* __restrict__ ss, double inv_cnt) {
  int c = threadIdx.x;
  if (c < 32) {
    double mu  = stats[c * 2 + 0] * inv_cnt;
    double var = stats[c * 2 + 1] * inv_cnt - mu * mu;
    double scale = (double)g[c] / sqrt(var + 1e-5);
    ss[c]      = (float)scale;
    ss[32 + c] = (float)((double)be[c] - mu * scale);
  }
}

__global__ void conv1_pool_k(const float* __restrict__ x, const float* __restrict__ W1,
                             const float* __restrict__ b1, const float* __restrict__ ss,
                             float* __restrict__ pool1) {
  int tid = blockIdx.x * 256 + threadIdx.x;        // 32*32*130*130 exact
  int px = tid % 130;
  int t = tid / 130;
  int py = t % 130; t /= 130;
  int c = t & 31, b = t >> 5;
  float w[27];
#pragma unroll
  for (int i = 0; i < 27; ++i) w[i] = W1[c * 27 + i];
  float bias = b1[c];
  float scale = ss[c], shift = ss[32 + c];
  float s00 = bias, s01 = bias, s10 = bias, s11 = bias;
  const float* xb = x + (size_t)b * 3 * 68644;
  int y0 = 2 * py, x0 = 2 * px;
#pragma unroll
  for (int ci = 0; ci < 3; ++ci) {
    float in[4][4];
    const float* ip = xb + ci * 68644 + y0 * 262 + x0;
#pragma unroll
    for (int r = 0; r < 4; ++r)
#pragma unroll
      for (int q = 0; q < 4; ++q) in[r][q] = ip[r * 262 + q];
#pragma unroll
    for (int dy = 0; dy < 3; ++dy)
#pragma unroll
      for (int dx = 0; dx < 3; ++dx) {
        float wv = w[ci * 9 + dy * 3 + dx];
        s00 += in[dy][dx]     * wv;
        s01 += in[dy][dx + 1] * wv;
        s10 += in[dy + 1][dx] * wv;
        s11 += in[dy + 1][dx + 1] * wv;
      }
  }
  float v00 = s00 * scale + shift, v01 = s01 * scale + shift;
  float v10 = s10 * scale + shift, v11 = s11 * scale + shift;
  float m = fmaxf(fmaxf(v00, v01), fmaxf(v10, v11));
  pool1[tid] = fmaxf(m, 0.f);
}

// ---------------- conv block 2 ----------------
__global__ void conv2_stats_k(const float* __restrict__ pool1, const float* __restrict__ W2,
                              const float* __restrict__ b2, double* __restrict__ stats) {
  __shared__ float w2s[288];
  __shared__ float sb1[4], sb2[4];
  int plane = blockIdx.y;
  int b = plane >> 5, c = plane & 31;
  for (int i = threadIdx.x; i < 288; i += 256) w2s[i] = W2[c * 288 + i];
  __syncthreads();
  int p = blockIdx.x * 256 + threadIdx.x;          // 64*256 = 16384 exact
  int y = p >> 7, xx = p & 127;
  const float* pb = pool1 + (size_t)b * 32 * 16900;   // 130*130
  float acc = b2[c];
  for (int ci = 0; ci < 32; ++ci) {
    const float* ip = pb + ci * 16900 + y * 130 + xx;
#pragma unroll
    for (int dy = 0; dy < 3; ++dy)
#pragma unroll
      for (int dx = 0; dx < 3; ++dx)
        acc += ip[dy * 130 + dx] * w2s[ci * 9 + dy * 3 + dx];
  }
  float s1 = acc, s2 = acc * acc;
#pragma unroll
  for (int o = 32; o > 0; o >>= 1) { s1 += __shfl_down(s1, o); s2 += __shfl_down(s2, o); }
  int wv = threadIdx.x >> 6;
  if ((threadIdx.x & 63) == 0) { sb1[wv] = s1; sb2[wv] = s2; }
  __syncthreads();
  if (threadIdx.x == 0) {
    float t1 = 0.f, t2 = 0.f;
    for (int i = 0; i < 4; ++i) { t1 += sb1[i]; t2 += sb2[i]; }
    atomicAdd(&stats[c * 2 + 0], (double)t1);
    atomicAdd(&stats[c * 2 + 1], (double)t2);
  }
}

__global__ void conv2_pool_k(const float* __restrict__ pool1, const float* __restrict__ W2,
                             const float* __restrict__ b2, const float* __restrict__ ss,
                             float* __restrict__ X) {
  __shared__ float w2s[9216];     // transposed: [(ci*9+k)*32 + c] -> conflict-free
  for (int i = threadIdx.x; i < 9216; i += 256) {
    int cc = i / 288, r = i - cc * 288;
    w2s[r * 32 + cc] = W2[i];
  }
  __syncthreads();
  int tid = blockIdx.x * 256 + threadIdx.x;        // 32*64*64*32 = 4,194,304
  int c = tid & 31;
  int t = tid >> 5;
  int px = t & 63; t >>= 6;
  int py = t & 63;
  int b = t >> 6;
  float scale = ss[c], shift = ss[32 + c];
  float bias = b2[c];
  float s00 = bias, s01 = bias, s10 = bias, s11 = bias;
  const float* pb = pool1 + (size_t)b * 32 * 16900 + (2 * py) * 130 + 2 * px;
  for (int ci = 0; ci < 32; ++ci) {
    const float* ip = pb + ci * 16900;
    float in[4][4];
#pragma unroll
    for (int r = 0; r < 4; ++r)
#pragma unroll
      for (int q = 0; q < 4; ++q) in[r][q] = ip[r * 130 + q];
#pragma unroll
    for (int dy = 0; dy < 3; ++dy)
#pragma unroll
      for (int dx = 0; dx < 3; ++dx) {
        float wv = w2s[(ci * 9 + dy * 3 + dx) * 32 + c];
        s00 += in[dy][dx]     * wv;
        s01 += in[dy][dx + 1] * wv;
        s10 += in[dy + 1][dx] * wv;
        s11 += in[dy + 1][dx + 1] * wv;
      }
  }
  float v00 = s00 * scale + shift, v01 = s01 * scale + shift;
  float v10 = s10 * scale + shift, v11 = s11 * scale + shift;
  float m = fmaxf(fmaxf(v00, v01), fmaxf(v10, v11));
  int node = b * 4096 + py * 64 + px;
  X[(size_t)node * 32 + c] = fmaxf(m, 0.f);
}

// ---------------- GAT layer kernels ----------------
// repack fW [2,F,2D] / wW [2,1,2D] into column-major-by-k panels WU/WV [D][S],
// S = 2F+2 (last 2 cols are the attention vectors). UB holds fb (+wb) bias.
__global__ void repack_k(const float* __restrict__ fW, const float* __restrict__ fb,
                         const float* __restrict__ wW, const float* __restrict__ wb,
                         float* __restrict__ WU, float* __restrict__ WV,
                         float* __restrict__ UB, unsigned* __restrict__ amax,
                         int D, int F) {
  int HF = 2 * F, S = HF + 2, D2 = 2 * D;
  int tid = blockIdx.x * 256 + threadIdx.x;
  if (tid < 2) amax[tid] = 0x007FFFFFu;          // enc(-inf)
  if (tid < S) UB[tid] = (tid < HF) ? fb[tid] : wb[tid - HF];
  if (tid >= D * S) return;
  int k = tid / S, c = tid - k * S;
  if (c < HF) {
    WU[k * S + c] = fW[(size_t)c * D2 + k];       // c = h*F+j, fW[h][j][k]
    WV[k * S + c] = fW[(size_t)c * D2 + D + k];
  } else {
    int h = c - HF;
    WU[k * S + c] = wW[(size_t)h * D2 + k];
    WV[k * S + c] = wW[(size_t)h * D2 + D + k];
  }
}

// U[n][c] = sum_k X[n][k]*WU[k][c] + UB[c];  V[n][c] = sum_k X[n][k]*WV[k][c]
__global__ void gemm_uv_k(const float* __restrict__ X, const float* __restrict__ WU,
                          const float* __restrict__ WV, const float* __restrict__ UB,
                          float* __restrict__ U, float* __restrict__ V, int D, int S) {
  int c = blockIdx.x * 64 + threadIdx.x;
  int cc = (c < S) ? c : (S - 1);
  int n0 = blockIdx.y * 4;
  float ub = UB[cc];
  float au0 = ub, au1 = ub, au2 = ub, au3 = ub;
  float av0 = 0.f, av1 = 0.f, av2 = 0.f, av3 = 0.f;
  const float* x0 = X + (size_t)n0 * D;
  for (int k = 0; k < D; ++k) {
    float wu = WU[k * S + cc];
    float wv = WV[k * S + cc];
    float xv0 = x0[k];
    float xv1 = x0[D + k];
    float xv2 = x0[2 * D + k];
    float xv3 = x0[3 * D + k];
    au0 += xv0 * wu; au1 += xv1 * wu; au2 += xv2 * wu; au3 += xv3 * wu;
    av0 += xv0 * wv; av1 += xv1 * wv; av2 += xv2 * wv; av3 += xv3 * wv;
  }
  if (c < S) {
    U[(size_t)(n0 + 0) * S + c] = au0;
    U[(size_t)(n0 + 1) * S + c] = au1;
    U[(size_t)(n0 + 2) * S + c] = au2;
    U[(size_t)(n0 + 3) * S + c] = au3;
    V[(size_t)(n0 + 0) * S + c] = av0;
    V[(size_t)(n0 + 1) * S + c] = av1;
    V[(size_t)(n0 + 2) * S + c] = av2;
    V[(size_t)(n0 + 3) * S + c] = av3;
  }
}

__global__ void edge_logit_k(const int* __restrict__ src, const int* __restrict__ tgt,
                             const float* __restrict__ U, const float* __restrict__ V,
                             float* __restrict__ aexp, unsigned* __restrict__ amax, int S) {
  int HF = S - 2;
  int e = blockIdx.x * 256 + threadIdx.x;       // E divisible by 256
  int s = src[e], t = tgt[e];
  float a0 = U[(size_t)s * S + HF]     + V[(size_t)t * S + HF];
  float a1 = U[(size_t)s * S + HF + 1] + V[(size_t)t * S + HF + 1];
  aexp[e * 2 + 0] = a0;
  aexp[e * 2 + 1] = a1;
#pragma unroll
  for (int o = 32; o > 0; o >>= 1) {
    a0 = fmaxf(a0, __shfl_down(a0, o));
    a1 = fmaxf(a1, __shfl_down(a1, o));
  }
  if ((threadIdx.x & 63) == 0) {
    atomicMax(&amax[0], enc_f(a0));
    atomicMax(&amax[1], enc_f(a1));
  }
}

__global__ void edge_exp_k(const int* __restrict__ tgt, float* __restrict__ aexp,
                           const unsigned* __restrict__ amax, float* __restrict__ den) {
  int e = blockIdx.x * 256 + threadIdx.x;
  float m0 = dec_f(amax[0]), m1 = dec_f(amax[1]);
  int t = tgt[e];
  float e0 = expf(aexp[e * 2 + 0] - m0);
  float e1 = expf(aexp[e * 2 + 1] - m1);
  aexp[e * 2 + 0] = e0;
  aexp[e * 2 + 1] = e1;
  atomicAdd(&den[t * 2 + 0], e0);
  atomicAdd(&den[t * 2 + 1], e1);
}

__global__ void edge_agg_k(const int* __restrict__ src, const int* __restrict__ tgt,
                           const float* __restrict__ U, const float* __restrict__ V,
                           const float* __restrict__ aexp, float* __restrict__ Xout,
                           int S, int F, int lHF) {
  int tid = blockIdx.x * 256 + threadIdx.x;     // E*HF total
  int HF = S - 2;
  int r = tid & (HF - 1);
  int e = tid >> lHF;
  int s = src[e], t = tgt[e];
  int h = (r >= F) ? 1 : 0;
  float ae = aexp[e * 2 + h];
  float y = U[(size_t)s * S + r] + V[(size_t)t * S + r];
  y = fmaxf(y, 0.f) * ae;
  atomicAdd(&Xout[(size_t)t * HF + r], y);
}

__global__ void norm_k(float* __restrict__ X, const float* __restrict__ den, int F, int lHF) {
  int tid = blockIdx.x * 256 + threadIdx.x;     // N*HF total
  int HF = 1 << lHF;
  int r = tid & (HF - 1);
  int n = tid >> lHF;
  int h = (r >= F) ? 1 : 0;
  X[tid] = X[tid] / (den[n * 2 + h] + 1e-6f);
}

// ---------------- pooling + MLP head ----------------
__global__ void graph_pool_k(const float* __restrict__ X, float* __restrict__ gp) {
  int g = blockIdx.y, chunk = blockIdx.x, j = threadIdx.x;   // 128 threads
  float acc = 0.f;
  int base = g * 4096 + chunk * 256;
  for (int i = 0; i < 256; ++i) acc += X[(size_t)(base + i) * 128 + j];
  atomicAdd(&gp[g * 128 + j], acc);
}

__global__ void mlp_k(const float* __restrict__ gp, const float* __restrict__ m1W,
                      const float* __restrict__ m1b, const float* __restrict__ m2W,
                      const float* __restrict__ m2b, float* __restrict__ out) {
  __shared__ float hid[1024];
  int tid = threadIdx.x;                       // 1024 threads
  int g = tid >> 5, j = tid & 31;
  float acc = m1b[j];
  for (int k = 0; k < 128; ++k) acc += gp[g * 128 + k] * m1W[j * 128 + k];
  hid[g * 32 + j] = fmaxf(acc, 0.f);
  __syncthreads();
  if (tid < 320) {
    int gg = tid / 10, c2 = tid - gg * 10;
    float o = m2b[c2];
    for (int k = 0; k < 32; ++k) o += hid[gg * 32 + k] * m2W[c2 * 32 + k];
    out[gg * 10 + c2] = o;
  }
}

// ---------------- driver ----------------
extern "C" void kernel_launch(void* const* d_in, const int* in_sizes, int n_in,
                              void* d_out, int out_size, void* d_ws, size_t ws_size,
                              hipStream_t stream) {
  (void)in_sizes; (void)n_in; (void)out_size; (void)ws_size;
  const float* x   = (const float*)d_in[0];
  const float* W1  = (const float*)d_in[1];
  const float* b1  = (const float*)d_in[2];
  const float* g1  = (const float*)d_in[3];
  const float* be1 = (const float*)d_in[4];
  const float* W2  = (const float*)d_in[5];
  const float* b2  = (const float*)d_in[6];
  const float* g2  = (const float*)d_in[7];
  const float* be2 = (const float*)d_in[8];
  const int* src = (const int*)d_in[25];
  const int* tgt = (const int*)d_in[26];

  float* ws   = (float*)d_ws;
  float* X    = ws + OFF_X;
  float* U    = ws + OFF_U;
  float* V    = ws + OFF_V;
  float* AEXP = ws + OFF_AEXP;
  float* DEN  = ws + OFF_DEN;
  float* WU   = ws + OFF_WU;
  float* WV   = ws + OFF_WV;
  float* UB   = ws + OFF_UB;
  double* STATS = (double*)(ws + OFF_STATS);
  float* SS   = ws + OFF_SS;
  float* GPOOL= ws + OFF_GPOOL;
  unsigned* AMAX = (unsigned*)(ws + OFF_AMAX);
  float* pool1 = U;   // aliases U: pool1 dead before L1 GEMM writes U

  // conv block 1 (two-pass: stats, then fused conv+BN+relu+maxpool)
  hipMemsetAsync(STATS, 0, 64 * sizeof(double), stream);
  conv1_stats_k<<<dim3(67, 1024), 256, 0, stream>>>(x, W1, b1, STATS);
  bn_finalize_k<<<1, 64, 0, stream>>>(STATS, g1, be1, SS, 1.0 / 2163200.0);   // 32*260*260
  conv1_pool_k<<<67600, 256, 0, stream>>>(x, W1, b1, SS, pool1);

  // conv block 2
  hipMemsetAsync(STATS, 0, 64 * sizeof(double), stream);
  conv2_stats_k<<<dim3(64, 1024), 256, 0, stream>>>(pool1, W2, b2, STATS);
  bn_finalize_k<<<1, 64, 0, stream>>>(STATS, g2, be2, SS, 1.0 / 524288.0);    // 32*128*128
  conv2_pool_k<<<16384, 256, 0, stream>>>(pool1, W2, b2, SS, X);              // writes x0 [N,32]

  // three GAT layers, X is both input and output (in-place across layer)
  for (int l = 0; l < 3; ++l) {
    int D  = (l == 0) ? 32 : (l == 1) ? 64 : 128;
    int F  = (l == 0) ? 32 : 64;
    int HF = 2 * F, S = HF + 2;
    int lHF = (l == 0) ? 6 : 7;
    const float* fW = (const float*)d_in[9  + l * 4];
    const float* fb = (const float*)d_in[10 + l * 4];
    const float* wW = (const float*)d_in[11 + l * 4];
    const float* wb = (const float*)d_in[12 + l * 4];

    repack_k<<<(D * S + 255) / 256, 256, 0, stream>>>(fW, fb, wW, wb, WU, WV, UB, AMAX, D, F);
    gemm_uv_k<<<dim3((S + 63) / 64, NNODES / 4), 64, 0, stream>>>(X, WU, WV, UB, U, V, D, S);
    hipMemsetAsync(X, 0, (size_t)NNODES * HF * sizeof(float), stream);
    hipMemsetAsync(DEN, 0, (size_t)NNODES * 2 * sizeof(float), stream);
    edge_logit_k<<<NEDGES / 256, 256, 0, stream>>>(src, tgt, U, V, AEXP, AMAX, S);
    edge_exp_k<<<NEDGES / 256, 256, 0, stream>>>(tgt, AEXP, AMAX, DEN);
    edge_agg_k<<<(NEDGES * HF) / 256, 256, 0, stream>>>(src, tgt, U, V, AEXP, X, S, F, lHF);
    norm_k<<<(NNODES * HF) / 256, 256, 0, stream>>>(X, DEN, F, lHF);
  }

  // graph sum-pool + MLP head
  hipMemsetAsync(GPOOL, 0, 4096 * sizeof(float), stream);
  graph_pool_k<<<dim3(16, 32), 128, 0, stream>>>(X, GPOOL);
  mlp_k<<<1, 1024, 0, stream>>>(GPOOL, (const float*)d_in[21], (const float*)d_in[22],
                                (const float*)d_in[23], (const float*)d_in[24], (float*)d_out);
}

// Round 3
// 1991.110 us; speedup vs baseline: 2.1346x; 2.1346x over previous
//
#include <hip/hip_runtime.h>
#include <math.h>

#define NNODES  131072
#define NEDGES  393216

// ---------------- workspace layout (float offsets) ----------------
// Total 52,203,844 floats (~208.8 MB) — strictly <= the R1-proven footprint.
static const size_t OFF_X     = 0;                        // [N,128] = 16,777,216
static const size_t OFF_U     = 16777216;                 // 17,305,600 (PR1/pool1 alias; U uses first 16.7M)
static const size_t OFF_PA    = OFF_U + 16777216;         // 524,288 in U-region slack (PR1 dead by then)
static const size_t OFF_GPOOL = OFF_PA;                   // 4,096 (PA dead by pooling time)
static const size_t OFF_V     = OFF_U + 17305600;         // 16,777,216 (PR2 alias, then gemm V)
static const size_t OFF_AEXP  = OFF_V + 16777216;         // E*2 = 786,432
static const size_t OFF_CUR   = OFF_AEXP + 786432;        // 131,072 ints
static const size_t OFF_CSRE  = OFF_CUR + 131072;         // E ints = 393,216
static const size_t OFF_WUV   = OFF_CSRE + 393216;        // 32,768
static const size_t OFF_UB    = OFF_WUV + 32768;          // 128
static const size_t OFF_STATS = OFF_UB + 128;             // 64 doubles = 128 floats
static const size_t OFF_SS    = OFF_STATS + 128;          // 64
static const size_t OFF_AMAX  = OFF_SS + 64;              // 4

__device__ inline unsigned enc_f(float f) {
  int b = __float_as_int(f);
  unsigned u = (unsigned)b;
  return (b >= 0) ? (u | 0x80000000u) : ~u;
}
__device__ inline float dec_f(unsigned e) {
  unsigned b = (e & 0x80000000u) ? (e & 0x7FFFFFFFu) : ~e;
  return __int_as_float((int)b);
}

// ---------------- conv block 1: fused conv + raw maxpool + stats ----------------
__global__ __launch_bounds__(256) void conv1_fused_k(const float* __restrict__ x,
    const float* __restrict__ W1, const float* __restrict__ b1,
    float* __restrict__ PR1, double* __restrict__ stats) {
  __shared__ float sb1[4], sb2[4];
  int plane = blockIdx.y;                  // b*32+c
  int b = plane >> 5, c = plane & 31;
  float w[27];
#pragma unroll
  for (int i = 0; i < 27; ++i) w[i] = W1[c * 27 + i];
  float bias = b1[c];
  int p = blockIdx.x * 256 + threadIdx.x;  // over 130*130 = 16900
  bool valid = p < 16900;
  float s1 = 0.f, s2 = 0.f;
  if (valid) {
    int py = p / 130, px = p - py * 130;
    const float* xb = x + (size_t)b * 3 * 68644;   // 262*262
    float s00 = bias, s01 = bias, s10 = bias, s11 = bias;
    int y0 = 2 * py, x0 = 2 * px;
#pragma unroll
    for (int ci = 0; ci < 3; ++ci) {
      float in[4][4];
      const float* ip = xb + ci * 68644 + y0 * 262 + x0;
#pragma unroll
      for (int r = 0; r < 4; ++r)
#pragma unroll
        for (int q = 0; q < 4; ++q) in[r][q] = ip[r * 262 + q];
#pragma unroll
      for (int dy = 0; dy < 3; ++dy)
#pragma unroll
        for (int dx = 0; dx < 3; ++dx) {
          float wv = w[ci * 9 + dy * 3 + dx];
          s00 += in[dy][dx]     * wv;
          s01 += in[dy][dx + 1] * wv;
          s10 += in[dy + 1][dx] * wv;
          s11 += in[dy + 1][dx + 1] * wv;
        }
    }
    s1 = s00 + s01 + s10 + s11;
    s2 = s00 * s00 + s01 * s01 + s10 * s10 + s11 * s11;
    PR1[(size_t)plane * 16900 + p] = fmaxf(fmaxf(s00, s01), fmaxf(s10, s11));
  }
#pragma unroll
  for (int o = 32; o > 0; o >>= 1) { s1 += __shfl_down(s1, o); s2 += __shfl_down(s2, o); }
  int wv = threadIdx.x >> 6;
  if ((threadIdx.x & 63) == 0) { sb1[wv] = s1; sb2[wv] = s2; }
  __syncthreads();
  if (threadIdx.x == 0) {
    float t1 = 0.f, t2 = 0.f;
    for (int i = 0; i < 4; ++i) { t1 += sb1[i]; t2 += sb2[i]; }
    atomicAdd(&stats[c * 2 + 0], (double)t1);
    atomicAdd(&stats[c * 2 + 1], (double)t2);
  }
}

__global__ void bn_finalize_k(const double* __restrict__ stats, const float* __restrict__ g,
                              const float* __restrict__ be, float* __restrict__ ss, double inv_cnt) {
  int c = threadIdx.x;
  if (c < 32) {
    double mu  = stats[c * 2 + 0] * inv_cnt;
    double var = stats[c * 2 + 1] * inv_cnt - mu * mu;
    double scale = (double)g[c] / sqrt(var + 1e-5);
    ss[c]      = (float)scale;
    ss[32 + c] = (float)((double)be[c] - mu * scale);
  }
}

__global__ void bn_relu1_k(float* __restrict__ PR1, const float* __restrict__ ss) {
  int plane = blockIdx.y;
  int c = plane & 31;
  int p = blockIdx.x * 256 + threadIdx.x;
  if (p >= 16900) return;
  size_t i = (size_t)plane * 16900 + p;
  PR1[i] = fmaxf(PR1[i] * ss[c] + ss[32 + c], 0.f);
}

// ---------------- conv block 2: fused conv + raw maxpool + stats(partials) ----------------
__global__ __launch_bounds__(256) void conv2_fused_k(const float* __restrict__ pool1,
    const float* __restrict__ W2, const float* __restrict__ b2,
    float* __restrict__ PR2, float* __restrict__ part) {
  __shared__ float w2s[9504];     // stride-33 pad: w2s[r*33+cc] -> conflict-free across c
  __shared__ float r1[256], r2[256];
  for (int i = threadIdx.x; i < 9216; i += 256) {
    int cc = i / 288, r = i - cc * 288;
    w2s[r * 33 + cc] = W2[i];
  }
  __syncthreads();
  int tid = blockIdx.x * 256 + threadIdx.x;        // 32*64*64*32 = 4,194,304
  int c = tid & 31;
  int t = tid >> 5;
  int px = t & 63; t >>= 6;
  int py = t & 63;
  int b = t >> 6;
  float bias = b2[c];
  float s00 = bias, s01 = bias, s10 = bias, s11 = bias;
  const float* pb = pool1 + (size_t)b * 32 * 16900 + (2 * py) * 130 + 2 * px;
  for (int ci = 0; ci < 32; ++ci) {
    const float* ip = pb + ci * 16900;
    float in[4][4];
#pragma unroll
    for (int r = 0; r < 4; ++r)
#pragma unroll
      for (int q = 0; q < 4; ++q) in[r][q] = ip[r * 130 + q];
#pragma unroll
    for (int dy = 0; dy < 3; ++dy)
#pragma unroll
      for (int dx = 0; dx < 3; ++dx) {
        float wv = w2s[(ci * 9 + dy * 3 + dx) * 33 + c];
        s00 += in[dy][dx]     * wv;
        s01 += in[dy][dx + 1] * wv;
        s10 += in[dy + 1][dx] * wv;
        s11 += in[dy + 1][dx + 1] * wv;
      }
  }
  PR2[tid] = fmaxf(fmaxf(s00, s01), fmaxf(s10, s11));
  r1[threadIdx.x] = s00 + s01 + s10 + s11;
  r2[threadIdx.x] = s00 * s00 + s01 * s01 + s10 * s10 + s11 * s11;
  __syncthreads();
  if (threadIdx.x < 32) {
    float a = 0.f, bq = 0.f;
    for (int p = 0; p < 8; ++p) { a += r1[p * 32 + threadIdx.x]; bq += r2[p * 32 + threadIdx.x]; }
    part[(size_t)blockIdx.x * 64 + threadIdx.x * 2 + 0] = a;
    part[(size_t)blockIdx.x * 64 + threadIdx.x * 2 + 1] = bq;
  }
}

__global__ void stats_reduce_k(const float* __restrict__ part, double* __restrict__ stats) {
  __shared__ double sd[256];
  int cnt = blockIdx.x;               // 0..63
  double s = 0.0;
  for (int b = threadIdx.x; b < 16384; b += 256) s += (double)part[(size_t)b * 64 + cnt];
  sd[threadIdx.x] = s;
  __syncthreads();
  for (int o = 128; o > 0; o >>= 1) { if (threadIdx.x < o) sd[threadIdx.x] += sd[threadIdx.x + o]; __syncthreads(); }
  if (threadIdx.x == 0) stats[cnt] = sd[0];
}

__global__ void bn_relu2_k(const float* __restrict__ PR2, const float* __restrict__ ss,
                           float* __restrict__ X) {
  int i = blockIdx.x * 256 + threadIdx.x;          // 4,194,304
  int c = i & 31;
  X[i] = fmaxf(PR2[i] * ss[c] + ss[32 + c], 0.f);
}

// ---------------- CSR build (tgt-sorted incoming edge lists) ----------------
__global__ void deg_k(const int* __restrict__ tgt, int* __restrict__ cur) {
  int e = blockIdx.x * 256 + threadIdx.x;
  atomicAdd(&cur[tgt[e]], 1);
}

__global__ void scan_k(int* __restrict__ cur) {       // 1 block, 1024 threads, 131072 entries
  __shared__ int ls[1024];
  int tid = threadIdx.x;
  int base = tid * 128;
  int sum = 0;
  for (int i = 0; i < 128; ++i) sum += cur[base + i];
  ls[tid] = sum;
  __syncthreads();
  for (int off = 1; off < 1024; off <<= 1) {
    int v = (tid >= off) ? ls[tid - off] : 0;
    __syncthreads();
    ls[tid] += v;
    __syncthreads();
  }
  int excl = ls[tid] - sum;
  for (int i = 0; i < 128; ++i) { int d = cur[base + i]; cur[base + i] = excl; excl += d; }
}

__global__ void scatter_k(const int* __restrict__ tgt, int* __restrict__ cur,
                          int* __restrict__ csre) {
  int e = blockIdx.x * 256 + threadIdx.x;
  int t = tgt[e];
  int pos = atomicAdd(&cur[t], 1);
  csre[pos] = e;                       // store edge id; src fetched via src[e] in gather
}
// after scatter: cur[t] == rowptr[t+1]; start(t) = (t==0)?0:cur[t-1]

// ---------------- GAT layer kernels ----------------
__global__ void repack2_k(const float* __restrict__ fW, const float* __restrict__ fb,
                          float* __restrict__ WUV, float* __restrict__ UB,
                          unsigned* __restrict__ amax, int D, int HF) {
  int NN = 2 * HF, D2 = 2 * D;
  int i = blockIdx.x * 256 + threadIdx.x;
  if (i < 2) amax[i] = 0x007FFFFFu;        // enc(-inf)
  if (i < HF) UB[i] = fb[i];
  if (i >= D * NN) return;
  int k = i / NN, j = i - k * NN;
  int half = (j >= HF) ? 1 : 0;
  int cc = j - half * HF;
  WUV[i] = fW[(size_t)cc * D2 + half * D + k];
}

// C[N x 2HF] = X[N x D] @ WUV[D x 2HF]; left half -> U (+bias), right half -> V
__global__ __launch_bounds__(256) void gemm_uv_k(const float* __restrict__ X,
    const float* __restrict__ WUV, const float* __restrict__ UB,
    float* __restrict__ U, float* __restrict__ V, int D, int HF) {
  const int NN = 2 * HF;
  __shared__ float As[16][68];   // [k][m]
  __shared__ float Bs[16][68];   // [k][n]
  int tid = threadIdx.x;
  int tx = tid & 15, ty = tid >> 4;
  int rm = blockIdx.y * 64;
  int cn = blockIdx.x * 64;
  float acc[4][4] = {};
  int ar = tid >> 2;             // 0..63 row
  int ak = (tid & 3) * 4;        // 0,4,8,12
  int bk = tid >> 4;             // 0..15
  int bj = (tid & 15) * 4;
  for (int kb = 0; kb < D; kb += 16) {
    float4 av = *(const float4*)&X[(size_t)(rm + ar) * D + kb + ak];
    float4 bv = *(const float4*)&WUV[(size_t)(kb + bk) * NN + cn + bj];
    __syncthreads();
    As[ak + 0][ar] = av.x; As[ak + 1][ar] = av.y; As[ak + 2][ar] = av.z; As[ak + 3][ar] = av.w;
    *(float4*)&Bs[bk][bj] = bv;
    __syncthreads();
#pragma unroll
    for (int k = 0; k < 16; ++k) {
      float4 a = *(float4*)&As[k][ty * 4];
      float4 b = *(float4*)&Bs[k][tx * 4];
      acc[0][0] += a.x * b.x; acc[0][1] += a.x * b.y; acc[0][2] += a.x * b.z; acc[0][3] += a.x * b.w;
      acc[1][0] += a.y * b.x; acc[1][1] += a.y * b.y; acc[1][2] += a.y * b.z; acc[1][3] += a.y * b.w;
      acc[2][0] += a.z * b.x; acc[2][1] += a.z * b.y; acc[2][2] += a.z * b.z; acc[2][3] += a.z * b.w;
      acc[3][0] += a.w * b.x; acc[3][1] += a.w * b.y; acc[3][2] += a.w * b.z; acc[3][3] += a.w * b.w;
    }
  }
  bool isU = (cn < HF);
  float4 ub = make_float4(0.f, 0.f, 0.f, 0.f);
  if (isU) ub = *(const float4*)&UB[cn + tx * 4];
  float* dstBase = isU ? (U + cn) : (V + (cn - HF));
#pragma unroll
  for (int i = 0; i < 4; ++i) {
    int row = rm + ty * 4 + i;
    float4 o = make_float4(acc[i][0] + ub.x, acc[i][1] + ub.y, acc[i][2] + ub.z, acc[i][3] + ub.w);
    *(float4*)&dstBase[(size_t)row * HF + tx * 4] = o;
  }
}

// per-node attention dots: PA[n] = {pu0+wb0, pu1+wb1, pv0, pv1}
__global__ void pvec_k(const float* __restrict__ X, const float* __restrict__ wW,
                       const float* __restrict__ wb, float* __restrict__ PA, int D) {
  __shared__ float PWs[4 * 132];
  int tid = threadIdx.x;              // 64
  int D2 = 2 * D;
  for (int i = tid; i < 4 * D; i += 64) {
    int v = i / D, k = i - v * D;
    PWs[v * 132 + k] = (v < 2) ? wW[v * D2 + k] : wW[(v - 2) * D2 + D + k];
  }
  __syncthreads();
  int v = tid & 3;
  int n = blockIdx.x * 16 + (tid >> 2);
  const float* xr = X + (size_t)n * D;
  float acc = 0.f;
  for (int k = 0; k < D; k += 4) {
    float4 xv = *(const float4*)&xr[k];
    acc += xv.x * PWs[v * 132 + k] + xv.y * PWs[v * 132 + k + 1]
         + xv.z * PWs[v * 132 + k + 2] + xv.w * PWs[v * 132 + k + 3];
  }
  if (v < 2) acc += wb[v];
  PA[(size_t)n * 4 + v] = acc;
}

__global__ void edge_logit_k(const int* __restrict__ src, const int* __restrict__ tgt,
                             const float* __restrict__ PA, float* __restrict__ aexp,
                             unsigned* __restrict__ amax) {
  int e = blockIdx.x * 256 + threadIdx.x;
  int s = src[e], t = tgt[e];
  float4 ps = *(const float4*)&PA[(size_t)s * 4];
  float4 pt = *(const float4*)&PA[(size_t)t * 4];
  float a0 = ps.x + pt.z;
  float a1 = ps.y + pt.w;
  aexp[e * 2 + 0] = a0;
  aexp[e * 2 + 1] = a1;
#pragma unroll
  for (int o = 32; o > 0; o >>= 1) {
    a0 = fmaxf(a0, __shfl_down(a0, o));
    a1 = fmaxf(a1, __shfl_down(a1, o));
  }
  if ((threadIdx.x & 63) == 0) {
    atomicMax(&amax[0], enc_f(a0));
    atomicMax(&amax[1], enc_f(a1));
  }
}

__global__ void edge_exp_k(float* __restrict__ aexp, const unsigned* __restrict__ amax) {
  int e = blockIdx.x * 256 + threadIdx.x;
  float m0 = dec_f(amax[0]), m1 = dec_f(amax[1]);
  float2 lg = *(float2*)&aexp[e * 2];
  lg.x = __expf(lg.x - m0);
  lg.y = __expf(lg.y - m1);
  *(float2*)&aexp[e * 2] = lg;
}

// fused: denominator + numerator + normalize; thread = (node, 4-channel group)
__global__ void gather_k(const int* __restrict__ cur, const int* __restrict__ csre,
                         const int* __restrict__ src, const float* __restrict__ aexp,
                         const float* __restrict__ U, const float* __restrict__ V,
                         float* __restrict__ X, int HF, int F, int lq) {
  int tid = blockIdx.x * 256 + threadIdx.x;
  int r4 = tid & ((HF >> 2) - 1);
  int t = tid >> lq;
  int r0 = r4 << 2;
  int h = (r0 >= F) ? 1 : 0;
  int start = (t == 0) ? 0 : cur[t - 1];
  int end = cur[t];
  float4 v4 = *(const float4*)&V[(size_t)t * HF + r0];
  float ax = 0.f, ay = 0.f, az = 0.f, aw = 0.f, den = 0.f;
  for (int e = start; e < end; ++e) {
    int eo = csre[e];
    int s = src[eo];
    float ae = aexp[(size_t)eo * 2 + h];
    den += ae;
    const float4 u4 = *(const float4*)&U[(size_t)s * HF + r0];
    ax += ae * fmaxf(u4.x + v4.x, 0.f);
    ay += ae * fmaxf(u4.y + v4.y, 0.f);
    az += ae * fmaxf(u4.z + v4.z, 0.f);
    aw += ae * fmaxf(u4.w + v4.w, 0.f);
  }
  float inv = 1.f / (den + 1e-6f);
  float4 o = make_float4(ax * inv, ay * inv, az * inv, aw * inv);
  *(float4*)&X[(size_t)t * HF + r0] = o;
}

// ---------------- pooling + MLP head ----------------
__global__ void graph_pool_k(const float* __restrict__ X, float* __restrict__ gp) {
  int g = blockIdx.y, chunk = blockIdx.x, j = threadIdx.x;   // 128 threads
  int base = g * 4096 + chunk * 128;
  float acc = 0.f;
  for (int i = 0; i < 128; ++i) acc += X[(size_t)(base + i) * 128 + j];
  atomicAdd(&gp[g * 128 + j], acc);
}

__global__ void mlp_k(const float* __restrict__ gp, const float* __restrict__ m1W,
                      const float* __restrict__ m1b, const float* __restrict__ m2W,
                      const float* __restrict__ m2b, float* __restrict__ out) {
  __shared__ float hid[1024];
  int tid = threadIdx.x;                       // 1024 threads
  int g = tid >> 5, j = tid & 31;
  float acc = m1b[j];
  for (int k = 0; k < 128; ++k) acc += gp[g * 128 + k] * m1W[j * 128 + k];
  hid[g * 32 + j] = fmaxf(acc, 0.f);
  __syncthreads();
  if (tid < 320) {
    int gg = tid / 10, c2 = tid - gg * 10;
    float o = m2b[c2];
    for (int k = 0; k < 32; ++k) o += hid[gg * 32 + k] * m2W[c2 * 32 + k];
    out[gg * 10 + c2] = o;
  }
}

// ---------------- driver ----------------
extern "C" void kernel_launch(void* const* d_in, const int* in_sizes, int n_in,
                              void* d_out, int out_size, void* d_ws, size_t ws_size,
                              hipStream_t stream) {
  (void)in_sizes; (void)n_in; (void)out_size; (void)ws_size;
  const float* x   = (const float*)d_in[0];
  const float* W1  = (const float*)d_in[1];
  const float* b1  = (const float*)d_in[2];
  const float* g1  = (const float*)d_in[3];
  const float* be1 = (const float*)d_in[4];
  const float* W2  = (const float*)d_in[5];
  const float* b2  = (const float*)d_in[6];
  const float* g2  = (const float*)d_in[7];
  const float* be2 = (const float*)d_in[8];
  const int* src = (const int*)d_in[25];
  const int* tgt = (const int*)d_in[26];

  float* ws = (float*)d_ws;
  float* X     = ws + OFF_X;
  float* PR1   = ws + OFF_U;        // conv1 pooled-raw / pool1 after bn_relu1
  float* U     = ws + OFF_U;        // gemm U output (PR1 dead by then)
  float* V     = ws + OFF_V;        // PR2 alias, then gemm V output
  float* AEXP  = ws + OFF_AEXP;
  float* PA    = ws + OFF_PA;       // in U-region slack beyond U's N*HF use
  int*   CUR   = (int*)(ws + OFF_CUR);
  int*   CSRE  = (int*)(ws + OFF_CSRE);
  float* WUV   = ws + OFF_WUV;
  float* UB    = ws + OFF_UB;
  double* STATS= (double*)(ws + OFF_STATS);
  float* SS    = ws + OFF_SS;
  float* GPOOL = ws + OFF_GPOOL;    // aliases dead PA at the end
  unsigned* AMAX = (unsigned*)(ws + OFF_AMAX);
  float* PART  = X;                 // conv2 stat partials (16384*64) in X, consumed pre-bn_relu2

  // conv block 1: single conv pass + stats, then elementwise BN+relu
  hipMemsetAsync(STATS, 0, 64 * sizeof(double), stream);
  conv1_fused_k<<<dim3(67, 1024), 256, 0, stream>>>(x, W1, b1, PR1, STATS);
  bn_finalize_k<<<1, 64, 0, stream>>>(STATS, g1, be1, SS, 1.0 / 2163200.0);   // 32*260*260
  bn_relu1_k<<<dim3(67, 1024), 256, 0, stream>>>(PR1, SS);

  // conv block 2: single conv pass + stat partials, reduce, elementwise BN+relu -> X[N,32]
  conv2_fused_k<<<16384, 256, 0, stream>>>(PR1, W2, b2, V, PART);
  stats_reduce_k<<<64, 256, 0, stream>>>(PART, STATS);
  bn_finalize_k<<<1, 64, 0, stream>>>(STATS, g2, be2, SS, 1.0 / 524288.0);    // 32*128*128
  bn_relu2_k<<<16384, 256, 0, stream>>>(V, SS, X);

  // CSR build (tgt-major incoming lists)
  hipMemsetAsync(CUR, 0, NNODES * sizeof(int), stream);
  deg_k<<<NEDGES / 256, 256, 0, stream>>>(tgt, CUR);
  scan_k<<<1, 1024, 0, stream>>>(CUR);
  scatter_k<<<NEDGES / 256, 256, 0, stream>>>(tgt, CUR, CSRE);

  // three GAT layers (X in-place across layers)
  for (int l = 0; l < 3; ++l) {
    int D  = (l == 0) ? 32 : (l == 1) ? 64 : 128;
    int F  = (l == 0) ? 32 : 64;
    int HF = 2 * F, NN = 2 * HF;
    int lq = (l == 0) ? 4 : 5;       // log2(HF/4)
    const float* fW = (const float*)d_in[9  + l * 4];
    const float* fb = (const float*)d_in[10 + l * 4];
    const float* wW = (const float*)d_in[11 + l * 4];
    const float* wb = (const float*)d_in[12 + l * 4];

    repack2_k<<<(D * NN + 255) / 256, 256, 0, stream>>>(fW, fb, WUV, UB, AMAX, D, HF);
    gemm_uv_k<<<dim3(NN / 64, NNODES / 64), 256, 0, stream>>>(X, WUV, UB, U, V, D, HF);
    pvec_k<<<NNODES / 16, 64, 0, stream>>>(X, wW, wb, PA, D);
    edge_logit_k<<<NEDGES / 256, 256, 0, stream>>>(src, tgt, PA, AEXP, AMAX);
    edge_exp_k<<<NEDGES / 256, 256, 0, stream>>>(AEXP, AMAX);
    gather_k<<<(NNODES * (HF / 4)) / 256, 256, 0, stream>>>(CUR, CSRE, src, AEXP, U, V, X, HF, F, lq);
  }

  // graph sum-pool + MLP head
  hipMemsetAsync(GPOOL, 0, 4096 * sizeof(float), stream);
  graph_pool_k<<<dim3(32, 32), 128, 0, stream>>>(X, GPOOL);
  mlp_k<<<1, 1024, 0, stream>>>(GPOOL, (const float*)d_in[21], (const float*)d_in[22],
                                (const float*)d_in[23], (const float*)d_in[24], (float*)d_out);
}

// Round 8
// 1346.338 us; speedup vs baseline: 3.1568x; 1.4789x over previous
//
#include <hip/hip_runtime.h>
#include <math.h>

#define NNODES  131072
#define NEDGES  393216

// ---------------- workspace layout (float offsets) ----------------
static const size_t OFF_X     = 0;                        // [N,128] = 16,777,216
static const size_t OFF_U     = 16777216;                 // 17,305,600 (PR1/pool1 alias; U uses first 16.7M)
static const size_t OFF_PA    = OFF_U + 16777216;         // 524,288 in U-region slack (PR1 dead by then)
static const size_t OFF_GPOOL = OFF_PA;                   // 4,096 (PA dead by pooling time)
static const size_t OFF_V     = OFF_U + 17305600;         // 16,777,216 (PR2 alias, then gemm V)
static const size_t OFF_AEXP  = OFF_V + 16777216;         // E*2 = 786,432
static const size_t OFF_CUR   = OFF_AEXP + 786432;        // 131,072 ints
static const size_t OFF_CSRE  = OFF_CUR + 131072;         // E ints = 393,216
static const size_t OFF_WUV   = OFF_CSRE + 393216;        // 32,768
static const size_t OFF_UB    = OFF_WUV + 32768;          // 128
static const size_t OFF_STATS = OFF_UB + 128;             // 64 doubles = 128 floats
static const size_t OFF_SS    = OFF_STATS + 128;          // 64
static const size_t OFF_AMAX  = OFF_SS + 64;              // 4
// X-region transient aliases (all dead before bn_relu2 writes X):
//   PART  = X + 0          (<= 9248*64 = 591,872 floats)
//   W1T   = X + 1,000,000  (864)
//   W2T   = X + 1,001,000  (9,216)

__device__ inline unsigned enc_f(float f) {
  int b = __float_as_int(f);
  unsigned u = (unsigned)b;
  return (b >= 0) ? (u | 0x80000000u) : ~u;
}
__device__ inline float dec_f(unsigned e) {
  unsigned b = (e & 0x80000000u) ? (e & 0x7FFFFFFFu) : ~e;
  return __int_as_float((int)b);
}

// ---------------- weight repack ----------------
__global__ void repackW1_k(const float* __restrict__ W1, float* __restrict__ W1T) {
  int i = blockIdx.x * 256 + threadIdx.x;      // 864 = 27*32
  if (i >= 864) return;
  int j = i >> 5, c = i & 31;
  W1T[i] = W1[c * 27 + j];                     // W1T[j][cout]
}

__global__ void repackW2_k(const float* __restrict__ W2, float* __restrict__ W2T) {
  int i = blockIdx.x * 256 + threadIdx.x;      // 9216 = 288*32
  if (i >= 9216) return;
  int j = i >> 5, c = i & 31;
  W2T[i] = W2[c * 288 + j];                    // W2T[ci*9+k][cout]
}

// ---------------- conv block 1: LDS-tiled conv + raw maxpool + stat partials ----------------
// grid (17,17,32); pooled tile 8x8; pool1 stored CHANNEL-LAST [b][130*130][32]
__global__ __launch_bounds__(256) void conv1_tiled_k(const float* __restrict__ x,
    const float* __restrict__ W1T, const float* __restrict__ b1,
    float* __restrict__ PR1, float* __restrict__ part) {
  __shared__ float in_t[972];                  // [ci][row*18+col], 3*18*18
  __shared__ float rs1[256], rs2[256];
  int tx = blockIdx.x, ty = blockIdx.y, b = blockIdx.z;
  int tid = threadIdx.x;
  int r0 = 16 * ty, c0 = 16 * tx;
  for (int idx = tid; idx < 972; idx += 256) {
    int ci = idx / 324, rc = idx - ci * 324;
    int row = rc / 18, col = rc - row * 18;
    int gr = r0 + row, gc = c0 + col;
    float v = 0.f;
    if (gr < 262 && gc < 262) v = x[(size_t)(b * 3 + ci) * 68644 + gr * 262 + gc];
    in_t[idx] = v;
  }
  __syncthreads();
  int c = tid & 31, pg = tid >> 5;
  float w[27];
#pragma unroll
  for (int j = 0; j < 27; ++j) w[j] = W1T[j * 32 + c];
  float bias = b1[c];
  int px = tx * 8 + pg;
  float s1 = 0.f, s2 = 0.f;
#pragma unroll
  for (int r = 0; r < 8; ++r) {
    int py = ty * 8 + r;
    if (py < 130 && px < 130) {
      float a00 = bias, a01 = bias, a10 = bias, a11 = bias;
#pragma unroll
      for (int ci = 0; ci < 3; ++ci) {
        const float* ip = &in_t[ci * 324 + (2 * r) * 18 + 2 * pg];
#pragma unroll
        for (int dy = 0; dy < 3; ++dy) {
#pragma unroll
          for (int dx = 0; dx < 3; ++dx) {
            float wv = w[ci * 9 + dy * 3 + dx];
            a00 += ip[dy * 18 + dx]           * wv;
            a01 += ip[dy * 18 + dx + 1]       * wv;
            a10 += ip[(dy + 1) * 18 + dx]     * wv;
            a11 += ip[(dy + 1) * 18 + dx + 1] * wv;
          }
        }
      }
      s1 += a00 + a01 + a10 + a11;
      s2 += a00 * a00 + a01 * a01 + a10 * a10 + a11 * a11;
      float m = fmaxf(fmaxf(a00, a01), fmaxf(a10, a11));
      PR1[((size_t)b * 16900 + py * 130 + px) * 32 + c] = m;
    }
  }
  rs1[tid] = s1; rs2[tid] = s2;
  __syncthreads();
  if (tid < 32) {
    float a = 0.f, q = 0.f;
    for (int g = 0; g < 8; ++g) { a += rs1[g * 32 + tid]; q += rs2[g * 32 + tid]; }
    int bid = (b * 17 + ty) * 17 + tx;
    part[(size_t)bid * 64 + tid * 2 + 0] = a;
    part[(size_t)bid * 64 + tid * 2 + 1] = q;
  }
}

__global__ void stats_reduce_k(const float* __restrict__ part, double* __restrict__ stats, int nb) {
  __shared__ double sd[256];
  int cnt = blockIdx.x;               // 0..63
  double s = 0.0;
  for (int b = threadIdx.x; b < nb; b += 256) s += (double)part[(size_t)b * 64 + cnt];
  sd[threadIdx.x] = s;
  __syncthreads();
  for (int o = 128; o > 0; o >>= 1) { if (threadIdx.x < o) sd[threadIdx.x] += sd[threadIdx.x + o]; __syncthreads(); }
  if (threadIdx.x == 0) stats[cnt] = sd[0];
}

__global__ void bn_finalize_k(const double* __restrict__ stats, const float* __restrict__ g,
                              const float* __restrict__ be, float* __restrict__ ss, double inv_cnt) {
  int c = threadIdx.x;
  if (c < 32) {
    double mu  = stats[c * 2 + 0] * inv_cnt;
    double var = stats[c * 2 + 1] * inv_cnt - mu * mu;
    double scale = (double)g[c] / sqrt(var + 1e-5);
    ss[c]      = (float)scale;
    ss[32 + c] = (float)((double)be[c] - mu * scale);
  }
}

__global__ void bn_relu1_k(float* __restrict__ PR1, const float* __restrict__ ss) {
  int i = blockIdx.x * 256 + threadIdx.x;      // 17,305,600 = 67600*256 exact
  int c = i & 31;                              // channel-last
  PR1[i] = fmaxf(PR1[i] * ss[c] + ss[32 + c], 0.f);
}

// ---------------- conv block 2: LDS-tiled conv + raw maxpool + stat partials ----------------
// grid (8,8,32); pooled tile 8x8 (64x64 exact); pool1 channel-last in, PR2 channel-last out
__global__ __launch_bounds__(256) void conv2_tiled_k(const float* __restrict__ pool1,
    const float* __restrict__ W2T, const float* __restrict__ b2,
    float* __restrict__ PR2, float* __restrict__ part) {
  __shared__ float in_t[10368];                // [(row*18+col)*32 + ci]
  __shared__ float rs1[256], rs2[256];
  int tx = blockIdx.x, ty = blockIdx.y, b = blockIdx.z;
  int tid = threadIdx.x;
  int r0 = 16 * ty, c0 = 16 * tx;
  const float* pb = pool1 + ((size_t)b * 16900 + r0 * 130 + c0) * 32;
  for (int idx = tid; idx < 10368; idx += 256) {
    int rc = idx >> 5, ci = idx & 31;
    int row = rc / 18, col = rc - row * 18;
    in_t[idx] = pb[(size_t)(row * 130 + col) * 32 + ci];
  }
  __syncthreads();
  int c = tid & 31, pg = tid >> 5;
  float bias = b2[c];
  float acc[8][4];
#pragma unroll
  for (int r = 0; r < 8; ++r) { acc[r][0] = bias; acc[r][1] = bias; acc[r][2] = bias; acc[r][3] = bias; }
  int cb = 2 * pg;                             // local conv col base
  float w[9], wn[9];
#pragma unroll
  for (int k = 0; k < 9; ++k) w[k] = W2T[k * 32 + c];
#pragma unroll 1
  for (int ci = 0; ci < 32; ++ci) {
    if (ci < 31) {
#pragma unroll
      for (int k = 0; k < 9; ++k) wn[k] = W2T[((ci + 1) * 9 + k) * 32 + c];
    }
    float r0v[4], r1v[4], r2v[4], r3v[4];
#pragma unroll
    for (int q = 0; q < 4; ++q) {
      r0v[q] = in_t[(0 * 18 + cb + q) * 32 + ci];
      r1v[q] = in_t[(1 * 18 + cb + q) * 32 + ci];
    }
#pragma unroll
    for (int r = 0; r < 8; ++r) {
#pragma unroll
      for (int q = 0; q < 4; ++q) {
        r2v[q] = in_t[((2 * r + 2) * 18 + cb + q) * 32 + ci];
        r3v[q] = in_t[((2 * r + 3) * 18 + cb + q) * 32 + ci];
      }
#pragma unroll
      for (int dx = 0; dx < 3; ++dx) {
        float w0 = w[dx], w1 = w[3 + dx], w2 = w[6 + dx];
        acc[r][0] += r0v[dx]     * w0 + r1v[dx]     * w1 + r2v[dx]     * w2;
        acc[r][1] += r0v[dx + 1] * w0 + r1v[dx + 1] * w1 + r2v[dx + 1] * w2;
        acc[r][2] += r1v[dx]     * w0 + r2v[dx]     * w1 + r3v[dx]     * w2;
        acc[r][3] += r1v[dx + 1] * w0 + r2v[dx + 1] * w1 + r3v[dx + 1] * w2;
      }
#pragma unroll
      for (int q = 0; q < 4; ++q) { r0v[q] = r2v[q]; r1v[q] = r3v[q]; }
    }
#pragma unroll
    for (int k = 0; k < 9; ++k) w[k] = wn[k];
  }
  float s1 = 0.f, s2 = 0.f;
  int px = tx * 8 + pg;
#pragma unroll
  for (int r = 0; r < 8; ++r) {
    s1 += acc[r][0] + acc[r][1] + acc[r][2] + acc[r][3];
    s2 += acc[r][0] * acc[r][0] + acc[r][1] * acc[r][1] + acc[r][2] * acc[r][2] + acc[r][3] * acc[r][3];
    int py = ty * 8 + r;
    float m = fmaxf(fmaxf(acc[r][0], acc[r][1]), fmaxf(acc[r][2], acc[r][3]));
    PR2[((size_t)b * 4096 + py * 64 + px) * 32 + c] = m;
  }
  rs1[tid] = s1; rs2[tid] = s2;
  __syncthreads();
  if (tid < 32) {
    float a = 0.f, q = 0.f;
    for (int g = 0; g < 8; ++g) { a += rs1[g * 32 + tid]; q += rs2[g * 32 + tid]; }
    int bid = (b * 8 + ty) * 8 + tx;
    part[(size_t)bid * 64 + tid * 2 + 0] = a;
    part[(size_t)bid * 64 + tid * 2 + 1] = q;
  }
}

__global__ void bn_relu2_k(const float* __restrict__ PR2, const float* __restrict__ ss,
                           float* __restrict__ X) {
  int i = blockIdx.x * 256 + threadIdx.x;      // 4,194,304; channel-last
  int c = i & 31;
  X[i] = fmaxf(PR2[i] * ss[c] + ss[32 + c], 0.f);
}

// ---------------- CSR build (tgt-sorted incoming edge lists) ----------------
__global__ void deg_k(const int* __restrict__ tgt, int* __restrict__ cur) {
  int e = blockIdx.x * 256 + threadIdx.x;
  atomicAdd(&cur[tgt[e]], 1);
}

__global__ void scan_k(int* __restrict__ cur) {       // 1 block, 1024 threads, 131072 entries
  __shared__ int ls[1024];
  int tid = threadIdx.x;
  int base = tid * 128;
  int sum = 0;
  for (int i = 0; i < 128; ++i) sum += cur[base + i];
  ls[tid] = sum;
  __syncthreads();
  for (int off = 1; off < 1024; off <<= 1) {
    int v = (tid >= off) ? ls[tid - off] : 0;
    __syncthreads();
    ls[tid] += v;
    __syncthreads();
  }
  int excl = ls[tid] - sum;
  for (int i = 0; i < 128; ++i) { int d = cur[base + i]; cur[base + i] = excl; excl += d; }
}

__global__ void scatter_k(const int* __restrict__ tgt, int* __restrict__ cur,
                          int* __restrict__ csre) {
  int e = blockIdx.x * 256 + threadIdx.x;
  int t = tgt[e];
  int pos = atomicAdd(&cur[t], 1);
  csre[pos] = e;                       // store edge id; src fetched via src[e] in gather
}
// after scatter: cur[t] == rowptr[t+1]; start(t) = (t==0)?0:cur[t-1]

// ---------------- GAT layer kernels ----------------
__global__ void repack2_k(const float* __restrict__ fW, const float* __restrict__ fb,
                          float* __restrict__ WUV, float* __restrict__ UB,
                          unsigned* __restrict__ amax, int D, int HF) {
  int NN = 2 * HF, D2 = 2 * D;
  int i = blockIdx.x * 256 + threadIdx.x;
  if (i < 2) amax[i] = 0x007FFFFFu;        // enc(-inf)
  if (i < HF) UB[i] = fb[i];
  if (i >= D * NN) return;
  int k = i / NN, j = i - k * NN;
  int half = (j >= HF) ? 1 : 0;
  int cc = j - half * HF;
  WUV[i] = fW[(size_t)cc * D2 + half * D + k];
}

// C[N x 2HF] = X[N x D] @ WUV[D x 2HF]; left half -> U (+bias), right half -> V
__global__ __launch_bounds__(256) void gemm_uv_k(const float* __restrict__ X,
    const float* __restrict__ WUV, const float* __restrict__ UB,
    float* __restrict__ U, float* __restrict__ V, int D, int HF) {
  const int NN = 2 * HF;
  __shared__ float As[16][68];   // [k][m]
  __shared__ float Bs[16][68];   // [k][n]
  int tid = threadIdx.x;
  int tx = tid & 15, ty = tid >> 4;
  int rm = blockIdx.y * 64;
  int cn = blockIdx.x * 64;
  float acc[4][4] = {};
  int ar = tid >> 2;             // 0..63 row
  int ak = (tid & 3) * 4;        // 0,4,8,12
  int bk = tid >> 4;             // 0..15
  int bj = (tid & 15) * 4;
  for (int kb = 0; kb < D; kb += 16) {
    float4 av = *(const float4*)&X[(size_t)(rm + ar) * D + kb + ak];
    float4 bv = *(const float4*)&WUV[(size_t)(kb + bk) * NN + cn + bj];
    __syncthreads();
    As[ak + 0][ar] = av.x; As[ak + 1][ar] = av.y; As[ak + 2][ar] = av.z; As[ak + 3][ar] = av.w;
    *(float4*)&Bs[bk][bj] = bv;
    __syncthreads();
#pragma unroll
    for (int k = 0; k < 16; ++k) {
      float4 a = *(float4*)&As[k][ty * 4];
      float4 b = *(float4*)&Bs[k][tx * 4];
      acc[0][0] += a.x * b.x; acc[0][1] += a.x * b.y; acc[0][2] += a.x * b.z; acc[0][3] += a.x * b.w;
      acc[1][0] += a.y * b.x; acc[1][1] += a.y * b.y; acc[1][2] += a.y * b.z; acc[1][3] += a.y * b.w;
      acc[2][0] += a.z * b.x; acc[2][1] += a.z * b.y; acc[2][2] += a.z * b.z; acc[2][3] += a.z * b.w;
      acc[3][0] += a.w * b.x; acc[3][1] += a.w * b.y; acc[3][2] += a.w * b.z; acc[3][3] += a.w * b.w;
    }
  }
  bool isU = (cn < HF);
  float4 ub = make_float4(0.f, 0.f, 0.f, 0.f);
  if (isU) ub = *(const float4*)&UB[cn + tx * 4];
  float* dstBase = isU ? (U + cn) : (V + (cn - HF));
#pragma unroll
  for (int i = 0; i < 4; ++i) {
    int row = rm + ty * 4 + i;
    float4 o = make_float4(acc[i][0] + ub.x, acc[i][1] + ub.y, acc[i][2] + ub.z, acc[i][3] + ub.w);
    *(float4*)&dstBase[(size_t)row * HF + tx * 4] = o;
  }
}

// per-node attention dots: PA[n] = {pu0+wb0, pu1+wb1, pv0, pv1}
__global__ void pvec_k(const float* __restrict__ X, const float* __restrict__ wW,
                       const float* __restrict__ wb, float* __restrict__ PA, int D) {
  __shared__ float PWs[4 * 132];
  int tid = threadIdx.x;              // 64
  int D2 = 2 * D;
  for (int i = tid; i < 4 * D; i += 64) {
    int v = i / D, k = i - v * D;
    PWs[v * 132 + k] = (v < 2) ? wW[v * D2 + k] : wW[(v - 2) * D2 + D + k];
  }
  __syncthreads();
  int v = tid & 3;
  int n = blockIdx.x * 16 + (tid >> 2);
  const float* xr = X + (size_t)n * D;
  float acc = 0.f;
  for (int k = 0; k < D; k += 4) {
    float4 xv = *(const float4*)&xr[k];
    acc += xv.x * PWs[v * 132 + k] + xv.y * PWs[v * 132 + k + 1]
         + xv.z * PWs[v * 132 + k + 2] + xv.w * PWs[v * 132 + k + 3];
  }
  if (v < 2) acc += wb[v];
  PA[(size_t)n * 4 + v] = acc;
}

__global__ void edge_logit_k(const int* __restrict__ src, const int* __restrict__ tgt,
                             const float* __restrict__ PA, float* __restrict__ aexp,
                             unsigned* __restrict__ amax) {
  int e = blockIdx.x * 256 + threadIdx.x;
  int s = src[e], t = tgt[e];
  float4 ps = *(const float4*)&PA[(size_t)s * 4];
  float4 pt = *(const float4*)&PA[(size_t)t * 4];
  float a0 = ps.x + pt.z;
  float a1 = ps.y + pt.w;
  aexp[e * 2 + 0] = a0;
  aexp[e * 2 + 1] = a1;
#pragma unroll
  for (int o = 32; o > 0; o >>= 1) {
    a0 = fmaxf(a0, __shfl_down(a0, o));
    a1 = fmaxf(a1, __shfl_down(a1, o));
  }
  if ((threadIdx.x & 63) == 0) {
    atomicMax(&amax[0], enc_f(a0));
    atomicMax(&amax[1], enc_f(a1));
  }
}

__global__ void edge_exp_k(float* __restrict__ aexp, const unsigned* __restrict__ amax) {
  int e = blockIdx.x * 256 + threadIdx.x;
  float m0 = dec_f(amax[0]), m1 = dec_f(amax[1]);
  float2 lg = *(float2*)&aexp[e * 2];
  lg.x = __expf(lg.x - m0);
  lg.y = __expf(lg.y - m1);
  *(float2*)&aexp[e * 2] = lg;
}

// fused: denominator + numerator + normalize; thread = (node, 4-channel group)
__global__ void gather_k(const int* __restrict__ cur, const int* __restrict__ csre,
                         const int* __restrict__ src, const float* __restrict__ aexp,
                         const float* __restrict__ U, const float* __restrict__ V,
                         float* __restrict__ X, int HF, int F, int lq) {
  int tid = blockIdx.x * 256 + threadIdx.x;
  int r4 = tid & ((HF >> 2) - 1);
  int t = tid >> lq;
  int r0 = r4 << 2;
  int h = (r0 >= F) ? 1 : 0;
  int start = (t == 0) ? 0 : cur[t - 1];
  int end = cur[t];
  float4 v4 = *(const float4*)&V[(size_t)t * HF + r0];
  float ax = 0.f, ay = 0.f, az = 0.f, aw = 0.f, den = 0.f;
  for (int e = start; e < end; ++e) {
    int eo = csre[e];
    int s = src[eo];
    float ae = aexp[(size_t)eo * 2 + h];
    den += ae;
    const float4 u4 = *(const float4*)&U[(size_t)s * HF + r0];
    ax += ae * fmaxf(u4.x + v4.x, 0.f);
    ay += ae * fmaxf(u4.y + v4.y, 0.f);
    az += ae * fmaxf(u4.z + v4.z, 0.f);
    aw += ae * fmaxf(u4.w + v4.w, 0.f);
  }
  float inv = 1.f / (den + 1e-6f);
  float4 o = make_float4(ax * inv, ay * inv, az * inv, aw * inv);
  *(float4*)&X[(size_t)t * HF + r0] = o;
}

// ---------------- pooling + MLP head ----------------
__global__ void graph_pool_k(const float* __restrict__ X, float* __restrict__ gp) {
  int g = blockIdx.y, chunk = blockIdx.x, j = threadIdx.x;   // 128 threads
  int base = g * 4096 + chunk * 128;
  float acc = 0.f;
  for (int i = 0; i < 128; ++i) acc += X[(size_t)(base + i) * 128 + j];
  atomicAdd(&gp[g * 128 + j], acc);
}

__global__ void mlp_k(const float* __restrict__ gp, const float* __restrict__ m1W,
                      const float* __restrict__ m1b, const float* __restrict__ m2W,
                      const float* __restrict__ m2b, float* __restrict__ out) {
  __shared__ float hid[1024];
  int tid = threadIdx.x;                       // 1024 threads
  int g = tid >> 5, j = tid & 31;
  float acc = m1b[j];
  for (int k = 0; k < 128; ++k) acc += gp[g * 128 + k] * m1W[j * 128 + k];
  hid[g * 32 + j] = fmaxf(acc, 0.f);
  __syncthreads();
  if (tid < 320) {
    int gg = tid / 10, c2 = tid - gg * 10;
    float o = m2b[c2];
    for (int k = 0; k < 32; ++k) o += hid[gg * 32 + k] * m2W[c2 * 32 + k];
    out[gg * 10 + c2] = o;
  }
}

// ---------------- driver ----------------
extern "C" void kernel_launch(void* const* d_in, const int* in_sizes, int n_in,
                              void* d_out, int out_size, void* d_ws, size_t ws_size,
                              hipStream_t stream) {
  (void)in_sizes; (void)n_in; (void)out_size; (void)ws_size;
  const float* x   = (const float*)d_in[0];
  const float* W1  = (const float*)d_in[1];
  const float* b1  = (const float*)d_in[2];
  const float* g1  = (const float*)d_in[3];
  const float* be1 = (const float*)d_in[4];
  const float* W2  = (const float*)d_in[5];
  const float* b2  = (const float*)d_in[6];
  const float* g2  = (const float*)d_in[7];
  const float* be2 = (const float*)d_in[8];
  const int* src = (const int*)d_in[25];
  const int* tgt = (const int*)d_in[26];

  float* ws = (float*)d_ws;
  float* X     = ws + OFF_X;
  float* PR1   = ws + OFF_U;        // conv1 pooled-raw / pool1 (channel-last) after bn_relu1
  float* U     = ws + OFF_U;        // gemm U output (PR1 dead by then)
  float* V     = ws + OFF_V;        // PR2 alias, then gemm V output
  float* AEXP  = ws + OFF_AEXP;
  float* PA    = ws + OFF_PA;       // in U-region slack beyond U's N*HF use
  int*   CUR   = (int*)(ws + OFF_CUR);
  int*   CSRE  = (int*)(ws + OFF_CSRE);
  float* WUV   = ws + OFF_WUV;
  float* UB    = ws + OFF_UB;
  double* STATS= (double*)(ws + OFF_STATS);
  float* SS    = ws + OFF_SS;
  float* GPOOL = ws + OFF_GPOOL;    // aliases dead PA at the end
  unsigned* AMAX = (unsigned*)(ws + OFF_AMAX);
  float* PART  = X;                 // conv stat partials; dead before bn_relu2
  float* W1T   = X + 1000000;       // repacked weights; dead before bn_relu2
  float* W2T   = X + 1001000;

  // weight repack
  repackW1_k<<<4, 256, 0, stream>>>(W1, W1T);
  repackW2_k<<<36, 256, 0, stream>>>(W2, W2T);

  // conv block 1: LDS-tiled conv pass + stat partials, reduce, elementwise BN+relu
  conv1_tiled_k<<<dim3(17, 17, 32), 256, 0, stream>>>(x, W1T, b1, PR1, PART);
  stats_reduce_k<<<64, 256, 0, stream>>>(PART, STATS, 9248);
  bn_finalize_k<<<1, 64, 0, stream>>>(STATS, g1, be1, SS, 1.0 / 2163200.0);   // 32*260*260
  bn_relu1_k<<<67600, 256, 0, stream>>>(PR1, SS);

  // conv block 2: LDS-tiled conv pass + stat partials, reduce, elementwise BN+relu -> X[N,32]
  conv2_tiled_k<<<dim3(8, 8, 32), 256, 0, stream>>>(PR1, W2T, b2, V, PART);
  stats_reduce_k<<<64, 256, 0, stream>>>(PART, STATS, 2048);
  bn_finalize_k<<<1, 64, 0, stream>>>(STATS, g2, be2, SS, 1.0 / 524288.0);    // 32*128*128
  bn_relu2_k<<<16384, 256, 0, stream>>>(V, SS, X);

  // CSR build (tgt-major incoming lists)
  hipMemsetAsync(CUR, 0, NNODES * sizeof(int), stream);
  deg_k<<<NEDGES / 256, 256, 0, stream>>>(tgt, CUR);
  scan_k<<<1, 1024, 0, stream>>>(CUR);
  scatter_k<<<NEDGES / 256, 256, 0, stream>>>(tgt, CUR, CSRE);

  // three GAT layers (X in-place across layers)
  for (int l = 0; l < 3; ++l) {
    int D  = (l == 0) ? 32 : (l == 1) ? 64 : 128;
    int F  = (l == 0) ? 32 : 64;
    int HF = 2 * F, NN = 2 * HF;
    int lq = (l == 0) ? 4 : 5;       // log2(HF/4)
    const float* fW = (const float*)d_in[9  + l * 4];
    const float* fb = (const float*)d_in[10 + l * 4];
    const float* wW = (const float*)d_in[11 + l * 4];
    const float* wb = (const float*)d_in[12 + l * 4];

    repack2_k<<<(D * NN + 255) / 256, 256, 0, stream>>>(fW, fb, WUV, UB, AMAX, D, HF);
    gemm_uv_k<<<dim3(NN / 64, NNODES / 64), 256, 0, stream>>>(X, WUV, UB, U, V, D, HF);
    pvec_k<<<NNODES / 16, 64, 0, stream>>>(X, wW, wb, PA, D);
    edge_logit_k<<<NEDGES / 256, 256, 0, stream>>>(src, tgt, PA, AEXP, AMAX);
    edge_exp_k<<<NEDGES / 256, 256, 0, stream>>>(AEXP, AMAX);
    gather_k<<<(NNODES * (HF / 4)) / 256, 256, 0, stream>>>(CUR, CSRE, src, AEXP, U, V, X, HF, F, lq);
  }

  // graph sum-pool + MLP head
  hipMemsetAsync(GPOOL, 0, 4096 * sizeof(float), stream);
  graph_pool_k<<<dim3(32, 32), 128, 0, stream>>>(X, GPOOL);
  mlp_k<<<1, 1024, 0, stream>>>(GPOOL, (const float*)d_in[21], (const float*)d_in[22],
                                (const float*)d_in[23], (const float*)d_in[24], (float*)d_out);
}

// Round 9
// 1308.958 us; speedup vs baseline: 3.2470x; 1.0286x over previous
//
#include <hip/hip_runtime.h>
#include <math.h>

#define NNODES  131072
#define NEDGES  393216

// ---------------- workspace layout (float offsets) ----------------
static const size_t OFF_X     = 0;                        // [N,128] = 16,777,216
static const size_t OFF_U     = 16777216;                 // 17,305,600 (PR1/pool1 alias; U uses first 16.7M)
static const size_t OFF_PA    = OFF_U + 16777216;         // 524,288 in U-region slack (PR1 dead by then)
static const size_t OFF_GPOOL = OFF_PA;                   // 4,096 (PA dead by pooling time)
static const size_t OFF_V     = OFF_U + 17305600;         // 16,777,216 (PR2 alias, then gemm V)
static const size_t OFF_AEXP  = OFF_V + 16777216;         // E*2 = 786,432
static const size_t OFF_CUR   = OFF_AEXP + 786432;        // 131,072 ints
static const size_t OFF_CSRE  = OFF_CUR + 131072;         // E ints = 393,216
static const size_t OFF_WUV   = OFF_CSRE + 393216;        // 32,768
static const size_t OFF_UB    = OFF_WUV + 32768;          // 128
static const size_t OFF_STATS = OFF_UB + 128;             // 64 doubles = 128 floats
static const size_t OFF_SS    = OFF_STATS + 128;          // 64
static const size_t OFF_AMAX  = OFF_SS + 64;              // 4
// X-region transient aliases (all dead before bn_relu2 writes X):
//   PART  = X + 0          (<= 9248*64 = 591,872 floats)
//   W1T   = X + 1,000,000  (864)
//   W2T   = X + 1,001,000  (9,216)

__device__ inline unsigned enc_f(float f) {
  int b = __float_as_int(f);
  unsigned u = (unsigned)b;
  return (b >= 0) ? (u | 0x80000000u) : ~u;
}
__device__ inline float dec_f(unsigned e) {
  unsigned b = (e & 0x80000000u) ? (e & 0x7FFFFFFFu) : ~e;
  return __int_as_float((int)b);
}

// ---------------- weight repack ----------------
__global__ void repackW1_k(const float* __restrict__ W1, float* __restrict__ W1T) {
  int i = blockIdx.x * 256 + threadIdx.x;      // 864 = 27*32
  if (i >= 864) return;
  int j = i >> 5, c = i & 31;
  W1T[i] = W1[c * 27 + j];                     // W1T[j][cout]
}

__global__ void repackW2_k(const float* __restrict__ W2, float* __restrict__ W2T) {
  int i = blockIdx.x * 256 + threadIdx.x;      // 9216 = 288*32
  if (i >= 9216) return;
  int j = i >> 5, c = i & 31;
  W2T[i] = W2[c * 288 + j];                    // W2T[ci*9+k][cout]
}

// ---------------- conv block 1: LDS-tiled conv + raw maxpool + stat partials ----------------
// grid (17,17,32); pooled tile 8x8; pool1 stored CHANNEL-LAST [b][130*130][32] (RAW, BN applied by conv2 stage)
__global__ __launch_bounds__(256) void conv1_tiled_k(const float* __restrict__ x,
    const float* __restrict__ W1T, const float* __restrict__ b1,
    float* __restrict__ PR1, float* __restrict__ part) {
  __shared__ float in_t[972];                  // [ci][row*18+col], 3*18*18
  __shared__ float rs1[256], rs2[256];
  int tx = blockIdx.x, ty = blockIdx.y, b = blockIdx.z;
  int tid = threadIdx.x;
  int r0 = 16 * ty, c0 = 16 * tx;
  for (int idx = tid; idx < 972; idx += 256) {
    int ci = idx / 324, rc = idx - ci * 324;
    int row = rc / 18, col = rc - row * 18;
    int gr = r0 + row, gc = c0 + col;
    float v = 0.f;
    if (gr < 262 && gc < 262) v = x[(size_t)(b * 3 + ci) * 68644 + gr * 262 + gc];
    in_t[idx] = v;
  }
  __syncthreads();
  int c = tid & 31, pg = tid >> 5;
  float w[27];
#pragma unroll
  for (int j = 0; j < 27; ++j) w[j] = W1T[j * 32 + c];
  float bias = b1[c];
  int px = tx * 8 + pg;
  float s1 = 0.f, s2 = 0.f;
#pragma unroll
  for (int r = 0; r < 8; ++r) {
    int py = ty * 8 + r;
    if (py < 130 && px < 130) {
      float a00 = bias, a01 = bias, a10 = bias, a11 = bias;
#pragma unroll
      for (int ci = 0; ci < 3; ++ci) {
        const float* ip = &in_t[ci * 324 + (2 * r) * 18 + 2 * pg];
#pragma unroll
        for (int dy = 0; dy < 3; ++dy) {
#pragma unroll
          for (int dx = 0; dx < 3; ++dx) {
            float wv = w[ci * 9 + dy * 3 + dx];
            a00 += ip[dy * 18 + dx]           * wv;
            a01 += ip[dy * 18 + dx + 1]       * wv;
            a10 += ip[(dy + 1) * 18 + dx]     * wv;
            a11 += ip[(dy + 1) * 18 + dx + 1] * wv;
          }
        }
      }
      s1 += a00 + a01 + a10 + a11;
      s2 += a00 * a00 + a01 * a01 + a10 * a10 + a11 * a11;
      float m = fmaxf(fmaxf(a00, a01), fmaxf(a10, a11));
      PR1[((size_t)b * 16900 + py * 130 + px) * 32 + c] = m;
    }
  }
  rs1[tid] = s1; rs2[tid] = s2;
  __syncthreads();
  if (tid < 32) {
    float a = 0.f, q = 0.f;
    for (int g = 0; g < 8; ++g) { a += rs1[g * 32 + tid]; q += rs2[g * 32 + tid]; }
    int bid = (b * 17 + ty) * 17 + tx;
    part[(size_t)bid * 64 + tid * 2 + 0] = a;
    part[(size_t)bid * 64 + tid * 2 + 1] = q;
  }
}

__global__ void stats_reduce_k(const float* __restrict__ part, double* __restrict__ stats, int nb) {
  __shared__ double sd[256];
  int cnt = blockIdx.x;               // 0..63
  double s = 0.0;
  for (int b = threadIdx.x; b < nb; b += 256) s += (double)part[(size_t)b * 64 + cnt];
  sd[threadIdx.x] = s;
  __syncthreads();
  for (int o = 128; o > 0; o >>= 1) { if (threadIdx.x < o) sd[threadIdx.x] += sd[threadIdx.x + o]; __syncthreads(); }
  if (threadIdx.x == 0) stats[cnt] = sd[0];
}

__global__ void bn_finalize_k(const double* __restrict__ stats, const float* __restrict__ g,
                              const float* __restrict__ be, float* __restrict__ ss, double inv_cnt) {
  int c = threadIdx.x;
  if (c < 32) {
    double mu  = stats[c * 2 + 0] * inv_cnt;
    double var = stats[c * 2 + 1] * inv_cnt - mu * mu;
    double scale = (double)g[c] / sqrt(var + 1e-5);
    ss[c]      = (float)scale;
    ss[32 + c] = (float)((double)be[c] - mu * scale);
  }
}

// ---------------- conv block 2: LDS-tiled conv (BN1+relu fused into stage) ----------------
// grid (8,8,32); pooled tile 8x8 (64x64 exact); pool1 RAW channel-last in, PR2 channel-last out
__global__ __launch_bounds__(256) void conv2_tiled_k(const float* __restrict__ pool1,
    const float* __restrict__ ss, const float* __restrict__ W2T, const float* __restrict__ b2,
    float* __restrict__ PR2, float* __restrict__ part) {
  __shared__ float in_t[10368];                // [(row*18+col)*32 + ci], post-BN1+relu
  __shared__ float rs1[256], rs2[256];
  __shared__ float ssl[64];
  int tx = blockIdx.x, ty = blockIdx.y, b = blockIdx.z;
  int tid = threadIdx.x;
  if (tid < 64) ssl[tid] = ss[tid];
  __syncthreads();
  int r0 = 16 * ty, c0 = 16 * tx;
  const float* pb = pool1 + ((size_t)b * 16900 + r0 * 130 + c0) * 32;
  for (int idx = tid; idx < 10368; idx += 256) {
    int rc = idx >> 5, ci = idx & 31;
    int row = rc / 18, col = rc - row * 18;
    float v = pb[(size_t)(row * 130 + col) * 32 + ci];
    in_t[idx] = fmaxf(v * ssl[ci] + ssl[32 + ci], 0.f);     // fused BN1 + relu
  }
  __syncthreads();
  int c = tid & 31, pg = tid >> 5;
  float bias = b2[c];
  float acc[8][4];
#pragma unroll
  for (int r = 0; r < 8; ++r) { acc[r][0] = bias; acc[r][1] = bias; acc[r][2] = bias; acc[r][3] = bias; }
  int cb = 2 * pg;                             // local conv col base
  float w[9], wn[9];
#pragma unroll
  for (int k = 0; k < 9; ++k) w[k] = W2T[k * 32 + c];
#pragma unroll 1
  for (int ci = 0; ci < 32; ++ci) {
    if (ci < 31) {
#pragma unroll
      for (int k = 0; k < 9; ++k) wn[k] = W2T[((ci + 1) * 9 + k) * 32 + c];
    }
    float r0v[4], r1v[4], r2v[4], r3v[4];
#pragma unroll
    for (int q = 0; q < 4; ++q) {
      r0v[q] = in_t[(0 * 18 + cb + q) * 32 + ci];
      r1v[q] = in_t[(1 * 18 + cb + q) * 32 + ci];
    }
#pragma unroll
    for (int r = 0; r < 8; ++r) {
#pragma unroll
      for (int q = 0; q < 4; ++q) {
        r2v[q] = in_t[((2 * r + 2) * 18 + cb + q) * 32 + ci];
        r3v[q] = in_t[((2 * r + 3) * 18 + cb + q) * 32 + ci];
      }
#pragma unroll
      for (int dx = 0; dx < 3; ++dx) {
        float w0 = w[dx], w1 = w[3 + dx], w2 = w[6 + dx];
        acc[r][0] += r0v[dx]     * w0 + r1v[dx]     * w1 + r2v[dx]     * w2;
        acc[r][1] += r0v[dx + 1] * w0 + r1v[dx + 1] * w1 + r2v[dx + 1] * w2;
        acc[r][2] += r1v[dx]     * w0 + r2v[dx]     * w1 + r3v[dx]     * w2;
        acc[r][3] += r1v[dx + 1] * w0 + r2v[dx + 1] * w1 + r3v[dx + 1] * w2;
      }
#pragma unroll
      for (int q = 0; q < 4; ++q) { r0v[q] = r2v[q]; r1v[q] = r3v[q]; }
    }
#pragma unroll
    for (int k = 0; k < 9; ++k) w[k] = wn[k];
  }
  float s1 = 0.f, s2 = 0.f;
  int px = tx * 8 + pg;
#pragma unroll
  for (int r = 0; r < 8; ++r) {
    s1 += acc[r][0] + acc[r][1] + acc[r][2] + acc[r][3];
    s2 += acc[r][0] * acc[r][0] + acc[r][1] * acc[r][1] + acc[r][2] * acc[r][2] + acc[r][3] * acc[r][3];
    int py = ty * 8 + r;
    float m = fmaxf(fmaxf(acc[r][0], acc[r][1]), fmaxf(acc[r][2], acc[r][3]));
    PR2[((size_t)b * 4096 + py * 64 + px) * 32 + c] = m;
  }
  rs1[tid] = s1; rs2[tid] = s2;
  __syncthreads();
  if (tid < 32) {
    float a = 0.f, q = 0.f;
    for (int g = 0; g < 8; ++g) { a += rs1[g * 32 + tid]; q += rs2[g * 32 + tid]; }
    int bid = (b * 8 + ty) * 8 + tx;
    part[(size_t)bid * 64 + tid * 2 + 0] = a;
    part[(size_t)bid * 64 + tid * 2 + 1] = q;
  }
}

__global__ void bn_relu2_k(const float* __restrict__ PR2, const float* __restrict__ ss,
                           float* __restrict__ X) {
  int i = blockIdx.x * 256 + threadIdx.x;      // 4,194,304; channel-last
  int c = i & 31;
  X[i] = fmaxf(PR2[i] * ss[c] + ss[32 + c], 0.f);
}

// ---------------- CSR build (tgt-sorted incoming edge lists) ----------------
__global__ void deg_k(const int* __restrict__ tgt, int* __restrict__ cur) {
  int e = blockIdx.x * 256 + threadIdx.x;
  atomicAdd(&cur[tgt[e]], 1);
}

__global__ void scan_k(int* __restrict__ cur) {       // 1 block, 1024 threads, 131072 entries
  __shared__ int ls[1024];
  int tid = threadIdx.x;
  int base = tid * 128;
  int sum = 0;
  for (int i = 0; i < 128; ++i) sum += cur[base + i];
  ls[tid] = sum;
  __syncthreads();
  for (int off = 1; off < 1024; off <<= 1) {
    int v = (tid >= off) ? ls[tid - off] : 0;
    __syncthreads();
    ls[tid] += v;
    __syncthreads();
  }
  int excl = ls[tid] - sum;
  for (int i = 0; i < 128; ++i) { int d = cur[base + i]; cur[base + i] = excl; excl += d; }
}

__global__ void scatter_k(const int* __restrict__ tgt, int* __restrict__ cur,
                          int* __restrict__ csre) {
  int e = blockIdx.x * 256 + threadIdx.x;
  int t = tgt[e];
  int pos = atomicAdd(&cur[t], 1);
  csre[pos] = e;                       // store edge id; src fetched via src[e] in gather
}
// after scatter: cur[t] == rowptr[t+1]; start(t) = (t==0)?0:cur[t-1]

// ---------------- GAT layer kernels ----------------
__global__ void repack2_k(const float* __restrict__ fW, const float* __restrict__ fb,
                          float* __restrict__ WUV, float* __restrict__ UB,
                          unsigned* __restrict__ amax, int D, int HF) {
  int NN = 2 * HF, D2 = 2 * D;
  int i = blockIdx.x * 256 + threadIdx.x;
  if (i < 2) amax[i] = 0x007FFFFFu;        // enc(-inf)
  if (i < HF) UB[i] = fb[i];
  if (i >= D * NN) return;
  int k = i / NN, j = i - k * NN;
  int half = (j >= HF) ? 1 : 0;
  int cc = j - half * HF;
  WUV[i] = fW[(size_t)cc * D2 + half * D + k];
}

// C[N x 2HF] = X[N x D] @ WUV[D x 2HF]; 128x64 tile, 8x4 acc/thread, BK=16
__global__ __launch_bounds__(256) void gemm_uv_k(const float* __restrict__ X,
    const float* __restrict__ WUV, const float* __restrict__ UB,
    float* __restrict__ U, float* __restrict__ V, int D, int HF) {
  const int NN = 2 * HF;
  __shared__ float As[16][132];  // [k][m], +4 pad
  __shared__ float Bs[16][68];   // [k][n]
  int tid = threadIdx.x;
  int tx = tid & 15, ty = tid >> 4;        // n = tx*4, m = ty*8
  int rm = blockIdx.y * 128;
  int cn = blockIdx.x * 64;
  float acc[8][4] = {};
  int ar = tid >> 1;             // 0..127 row
  int ak = (tid & 1) * 8;        // 0 or 8
  int bk = tid >> 4;             // 0..15
  int bj = (tid & 15) * 4;
  for (int kb = 0; kb < D; kb += 16) {
    const float* xr = &X[(size_t)(rm + ar) * D + kb + ak];
    float4 a0 = *(const float4*)&xr[0];
    float4 a1 = *(const float4*)&xr[4];
    float4 bv = *(const float4*)&WUV[(size_t)(kb + bk) * NN + cn + bj];
    __syncthreads();
    As[ak + 0][ar] = a0.x; As[ak + 1][ar] = a0.y; As[ak + 2][ar] = a0.z; As[ak + 3][ar] = a0.w;
    As[ak + 4][ar] = a1.x; As[ak + 5][ar] = a1.y; As[ak + 6][ar] = a1.z; As[ak + 7][ar] = a1.w;
    *(float4*)&Bs[bk][bj] = bv;
    __syncthreads();
#pragma unroll
    for (int k = 0; k < 16; ++k) {
      float4 am0 = *(float4*)&As[k][ty * 8];
      float4 am1 = *(float4*)&As[k][ty * 8 + 4];
      float4 b = *(float4*)&Bs[k][tx * 4];
      acc[0][0] += am0.x * b.x; acc[0][1] += am0.x * b.y; acc[0][2] += am0.x * b.z; acc[0][3] += am0.x * b.w;
      acc[1][0] += am0.y * b.x; acc[1][1] += am0.y * b.y; acc[1][2] += am0.y * b.z; acc[1][3] += am0.y * b.w;
      acc[2][0] += am0.z * b.x; acc[2][1] += am0.z * b.y; acc[2][2] += am0.z * b.z; acc[2][3] += am0.z * b.w;
      acc[3][0] += am0.w * b.x; acc[3][1] += am0.w * b.y; acc[3][2] += am0.w * b.z; acc[3][3] += am0.w * b.w;
      acc[4][0] += am1.x * b.x; acc[4][1] += am1.x * b.y; acc[4][2] += am1.x * b.z; acc[4][3] += am1.x * b.w;
      acc[5][0] += am1.y * b.x; acc[5][1] += am1.y * b.y; acc[5][2] += am1.y * b.z; acc[5][3] += am1.y * b.w;
      acc[6][0] += am1.z * b.x; acc[6][1] += am1.z * b.y; acc[6][2] += am1.z * b.z; acc[6][3] += am1.z * b.w;
      acc[7][0] += am1.w * b.x; acc[7][1] += am1.w * b.y; acc[7][2] += am1.w * b.z; acc[7][3] += am1.w * b.w;
    }
  }
  bool isU = (cn < HF);
  float4 ub = make_float4(0.f, 0.f, 0.f, 0.f);
  if (isU) ub = *(const float4*)&UB[cn + tx * 4];
  float* dstBase = isU ? (U + cn) : (V + (cn - HF));
#pragma unroll
  for (int i = 0; i < 8; ++i) {
    int row = rm + ty * 8 + i;
    float4 o = make_float4(acc[i][0] + ub.x, acc[i][1] + ub.y, acc[i][2] + ub.z, acc[i][3] + ub.w);
    *(float4*)&dstBase[(size_t)row * HF + tx * 4] = o;
  }
}

// per-node attention dots: PA[n] = {pu0+wb0, pu1+wb1, pv0, pv1}
__global__ void pvec_k(const float* __restrict__ X, const float* __restrict__ wW,
                       const float* __restrict__ wb, float* __restrict__ PA, int D) {
  __shared__ float PWs[4 * 132];
  int tid = threadIdx.x;              // 64
  int D2 = 2 * D;
  for (int i = tid; i < 4 * D; i += 64) {
    int v = i / D, k = i - v * D;
    PWs[v * 132 + k] = (v < 2) ? wW[v * D2 + k] : wW[(v - 2) * D2 + D + k];
  }
  __syncthreads();
  int v = tid & 3;
  int n = blockIdx.x * 16 + (tid >> 2);
  const float* xr = X + (size_t)n * D;
  float acc = 0.f;
  for (int k = 0; k < D; k += 4) {
    float4 xv = *(const float4*)&xr[k];
    acc += xv.x * PWs[v * 132 + k] + xv.y * PWs[v * 132 + k + 1]
         + xv.z * PWs[v * 132 + k + 2] + xv.w * PWs[v * 132 + k + 3];
  }
  if (v < 2) acc += wb[v];
  PA[(size_t)n * 4 + v] = acc;
}

__global__ void edge_logit_k(const int* __restrict__ src, const int* __restrict__ tgt,
                             const float* __restrict__ PA, float* __restrict__ aexp,
                             unsigned* __restrict__ amax) {
  int e = blockIdx.x * 256 + threadIdx.x;
  int s = src[e], t = tgt[e];
  float4 ps = *(const float4*)&PA[(size_t)s * 4];
  float4 pt = *(const float4*)&PA[(size_t)t * 4];
  float a0 = ps.x + pt.z;
  float a1 = ps.y + pt.w;
  aexp[e * 2 + 0] = a0;
  aexp[e * 2 + 1] = a1;
#pragma unroll
  for (int o = 32; o > 0; o >>= 1) {
    a0 = fmaxf(a0, __shfl_down(a0, o));
    a1 = fmaxf(a1, __shfl_down(a1, o));
  }
  if ((threadIdx.x & 63) == 0) {
    atomicMax(&amax[0], enc_f(a0));
    atomicMax(&amax[1], enc_f(a1));
  }
}

__global__ void edge_exp_k(float* __restrict__ aexp, const unsigned* __restrict__ amax) {
  int e = blockIdx.x * 256 + threadIdx.x;
  float m0 = dec_f(amax[0]), m1 = dec_f(amax[1]);
  float2 lg = *(float2*)&aexp[e * 2];
  lg.x = __expf(lg.x - m0);
  lg.y = __expf(lg.y - m1);
  *(float2*)&aexp[e * 2] = lg;
}

// fused: denominator + numerator + normalize; thread = (node, 4-channel group)
__global__ void gather_k(const int* __restrict__ cur, const int* __restrict__ csre,
                         const int* __restrict__ src, const float* __restrict__ aexp,
                         const float* __restrict__ U, const float* __restrict__ V,
                         float* __restrict__ X, int HF, int F, int lq) {
  int tid = blockIdx.x * 256 + threadIdx.x;
  int r4 = tid & ((HF >> 2) - 1);
  int t = tid >> lq;
  int r0 = r4 << 2;
  int h = (r0 >= F) ? 1 : 0;
  int start = (t == 0) ? 0 : cur[t - 1];
  int end = cur[t];
  float4 v4 = *(const float4*)&V[(size_t)t * HF + r0];
  float ax = 0.f, ay = 0.f, az = 0.f, aw = 0.f, den = 0.f;
  for (int e = start; e < end; ++e) {
    int eo = csre[e];
    int s = src[eo];
    float ae = aexp[(size_t)eo * 2 + h];
    den += ae;
    const float4 u4 = *(const float4*)&U[(size_t)s * HF + r0];
    ax += ae * fmaxf(u4.x + v4.x, 0.f);
    ay += ae * fmaxf(u4.y + v4.y, 0.f);
    az += ae * fmaxf(u4.z + v4.z, 0.f);
    aw += ae * fmaxf(u4.w + v4.w, 0.f);
  }
  float inv = 1.f / (den + 1e-6f);
  float4 o = make_float4(ax * inv, ay * inv, az * inv, aw * inv);
  *(float4*)&X[(size_t)t * HF + r0] = o;
}

// ---------------- pooling + MLP head ----------------
__global__ void graph_pool_k(const float* __restrict__ X, float* __restrict__ gp) {
  int g = blockIdx.y, chunk = blockIdx.x, j = threadIdx.x;   // 128 threads
  int base = g * 4096 + chunk * 128;
  float acc = 0.f;
  for (int i = 0; i < 128; ++i) acc += X[(size_t)(base + i) * 128 + j];
  atomicAdd(&gp[g * 128 + j], acc);
}

__global__ void mlp_k(const float* __restrict__ gp, const float* __restrict__ m1W,
                      const float* __restrict__ m1b, const float* __restrict__ m2W,
                      const float* __restrict__ m2b, float* __restrict__ out) {
  __shared__ float hid[1024];
  int tid = threadIdx.x;                       // 1024 threads
  int g = tid >> 5, j = tid & 31;
  float acc = m1b[j];
  for (int k = 0; k < 128; ++k) acc += gp[g * 128 + k] * m1W[j * 128 + k];
  hid[g * 32 + j] = fmaxf(acc, 0.f);
  __syncthreads();
  if (tid < 320) {
    int gg = tid / 10, c2 = tid - gg * 10;
    float o = m2b[c2];
    for (int k = 0; k < 32; ++k) o += hid[gg * 32 + k] * m2W[c2 * 32 + k];
    out[gg * 10 + c2] = o;
  }
}

// ---------------- driver ----------------
extern "C" void kernel_launch(void* const* d_in, const int* in_sizes, int n_in,
                              void* d_out, int out_size, void* d_ws, size_t ws_size,
                              hipStream_t stream) {
  (void)in_sizes; (void)n_in; (void)out_size; (void)ws_size;
  const float* x   = (const float*)d_in[0];
  const float* W1  = (const float*)d_in[1];
  const float* b1  = (const float*)d_in[2];
  const float* g1  = (const float*)d_in[3];
  const float* be1 = (const float*)d_in[4];
  const float* W2  = (const float*)d_in[5];
  const float* b2  = (const float*)d_in[6];
  const float* g2  = (const float*)d_in[7];
  const float* be2 = (const float*)d_in[8];
  const int* src = (const int*)d_in[25];
  const int* tgt = (const int*)d_in[26];

  float* ws = (float*)d_ws;
  float* X     = ws + OFF_X;
  float* PR1   = ws + OFF_U;        // conv1 pooled-raw (channel-last); BN1 applied in conv2 stage
  float* U     = ws + OFF_U;        // gemm U output (PR1 dead by then)
  float* V     = ws + OFF_V;        // PR2 alias, then gemm V output
  float* AEXP  = ws + OFF_AEXP;
  float* PA    = ws + OFF_PA;       // in U-region slack beyond U's N*HF use
  int*   CUR   = (int*)(ws + OFF_CUR);
  int*   CSRE  = (int*)(ws + OFF_CSRE);
  float* WUV   = ws + OFF_WUV;
  float* UB    = ws + OFF_UB;
  double* STATS= (double*)(ws + OFF_STATS);
  float* SS    = ws + OFF_SS;
  float* GPOOL = ws + OFF_GPOOL;    // aliases dead PA at the end
  unsigned* AMAX = (unsigned*)(ws + OFF_AMAX);
  float* PART  = X;                 // conv stat partials; dead before bn_relu2
  float* W1T   = X + 1000000;       // repacked weights; dead before bn_relu2
  float* W2T   = X + 1001000;

  // weight repack
  repackW1_k<<<4, 256, 0, stream>>>(W1, W1T);
  repackW2_k<<<36, 256, 0, stream>>>(W2, W2T);

  // conv block 1: LDS-tiled conv pass (raw pooled out) + stat partials, reduce -> SS (BN1)
  conv1_tiled_k<<<dim3(17, 17, 32), 256, 0, stream>>>(x, W1T, b1, PR1, PART);
  stats_reduce_k<<<64, 256, 0, stream>>>(PART, STATS, 9248);
  bn_finalize_k<<<1, 64, 0, stream>>>(STATS, g1, be1, SS, 1.0 / 2163200.0);   // 32*260*260

  // conv block 2: BN1+relu fused into stage; stat partials, reduce, elementwise BN2+relu -> X[N,32]
  conv2_tiled_k<<<dim3(8, 8, 32), 256, 0, stream>>>(PR1, SS, W2T, b2, V, PART);
  stats_reduce_k<<<64, 256, 0, stream>>>(PART, STATS, 2048);
  bn_finalize_k<<<1, 64, 0, stream>>>(STATS, g2, be2, SS, 1.0 / 524288.0);    // 32*128*128
  bn_relu2_k<<<16384, 256, 0, stream>>>(V, SS, X);

  // CSR build (tgt-major incoming lists)
  hipMemsetAsync(CUR, 0, NNODES * sizeof(int), stream);
  deg_k<<<NEDGES / 256, 256, 0, stream>>>(tgt, CUR);
  scan_k<<<1, 1024, 0, stream>>>(CUR);
  scatter_k<<<NEDGES / 256, 256, 0, stream>>>(tgt, CUR, CSRE);

  // three GAT layers (X in-place across layers)
  for (int l = 0; l < 3; ++l) {
    int D  = (l == 0) ? 32 : (l == 1) ? 64 : 128;
    int F  = (l == 0) ? 32 : 64;
    int HF = 2 * F, NN = 2 * HF;
    int lq = (l == 0) ? 4 : 5;       // log2(HF/4)
    const float* fW = (const float*)d_in[9  + l * 4];
    const float* fb = (const float*)d_in[10 + l * 4];
    const float* wW = (const float*)d_in[11 + l * 4];
    const float* wb = (const float*)d_in[12 + l * 4];

    repack2_k<<<(D * NN + 255) / 256, 256, 0, stream>>>(fW, fb, WUV, UB, AMAX, D, HF);
    gemm_uv_k<<<dim3(NN / 64, NNODES / 128), 256, 0, stream>>>(X, WUV, UB, U, V, D, HF);
    pvec_k<<<NNODES / 16, 64, 0, stream>>>(X, wW, wb, PA, D);
    edge_logit_k<<<NEDGES / 256, 256, 0, stream>>>(src, tgt, PA, AEXP, AMAX);
    edge_exp_k<<<NEDGES / 256, 256, 0, stream>>>(AEXP, AMAX);
    gather_k<<<(NNODES * (HF / 4)) / 256, 256, 0, stream>>>(CUR, CSRE, src, AEXP, U, V, X, HF, F, lq);
  }

  // graph sum-pool + MLP head
  hipMemsetAsync(GPOOL, 0, 4096 * sizeof(float), stream);
  graph_pool_k<<<dim3(32, 32), 128, 0, stream>>>(X, GPOOL);
  mlp_k<<<1, 1024, 0, stream>>>(GPOOL, (const float*)d_in[21], (const float*)d_in[22],
                                (const float*)d_in[23], (const float*)d_in[24], (float*)d_out);
}